// Round 3
// baseline (373.954 us; speedup 1.0000x reference)
//
#include <hip/hip_runtime.h>

typedef __bf16 bf16x8 __attribute__((ext_vector_type(8)));
typedef short short4v __attribute__((ext_vector_type(4)));
typedef float f32x4 __attribute__((ext_vector_type(4)));

#define MFMA32 __builtin_amdgcn_mfma_f32_16x16x32_bf16
#define MFMA16K __builtin_amdgcn_mfma_f32_16x16x16bf16_1k

#define KPAD 576
#define LOG2E 1.44269504f

__device__ __forceinline__ unsigned short f2bf(float f) {
  unsigned u = __float_as_uint(f);
  u += 0x7FFFu + ((u >> 16) & 1u);
  return (unsigned short)(u >> 16);
}

// ---------------- pack kernels ----------------

__global__ void k_pack_posed(const float* __restrict__ feat, const float* __restrict__ coord,
                             unsigned short* __restrict__ dst, int rows) {
  int i = blockIdx.x * 256 + threadIdx.x;
  int total = rows * KPAD;
  if (i >= total) return;
  int r = i / KPAD, c = i - r * KPAD;
  float v = 0.f;
  if (c < 512) v = feat[(size_t)r * 512 + c];
  else if (c < 515) v = coord[(size_t)r * 3 + (c - 512)];
  dst[i] = f2bf(v);
}

__global__ void k_pack_wT(const float* __restrict__ w, unsigned short* __restrict__ dst,
                          int kin, int nout) {
  int i = blockIdx.x * 256 + threadIdx.x;
  if (i >= nout * KPAD) return;
  int n = i / KPAD, kc = i - n * KPAD;
  float v = (kc < kin) ? w[(size_t)kc * nout + n] : 0.f;
  dst[i] = f2bf(v);
}

// coord head (h=8) of q/k buffer; cs!=null -> fold cscale*log2e (q side)
__global__ void k_pack_ch(const float* __restrict__ coord, unsigned short* __restrict__ buf,
                          const float* __restrict__ cs) {
  int i = blockIdx.x * 256 + threadIdx.x;
  if (i >= 4096 * 64) return;
  int row = i >> 6, d = i & 63;
  int b = row >> 11, n = row & 2047;
  float sc = cs ? cs[0] * LOG2E : 1.f;
  float v = (d < 3) ? coord[(size_t)row * 3 + d] * sc : 0.f;
  buf[(((size_t)b * 9 + 8) * 2048 + n) * 64 + d] = f2bf(v);
}

// ---------------- GEMM: C[m,n] = sum_k A[m,k]*BT[n,k], K=KPAD ----------------
// 64x32 tile, 4 waves (wave: 16 rows x 32 cols), register double-buffer.
// MODE 0: bf16 -> q/k layout  dst[((b*9+h)*2048+seq)*64+d], col=(h*64+d), *oscale
// MODE 1: bf16 -> vT layout   dst[((b*9+h)*64+d)*2048+seq]
// MODE 2: f32 row-major       dst[m*Nout+col]
template <int MODE>
__global__ __launch_bounds__(256) void k_gemm(const unsigned short* __restrict__ A,
                                              const unsigned short* __restrict__ BT,
                                              void* __restrict__ dstv, int Nout, float oscale) {
  const int m0 = blockIdx.x * 64;
  const int n0 = blockIdx.y * 32;
  const int wave = threadIdx.x >> 6;
  const int lane = threadIdx.x & 63;
  const int li = lane & 15, g = lane >> 4;

  const unsigned short* ap = A + (size_t)(m0 + wave * 16 + li) * KPAD + g * 8;
  const unsigned short* bp = BT + (size_t)(n0 + li) * KPAD + g * 8;

  bf16x8 af[2], bfr[2][2];
  af[0] = *(const bf16x8*)ap;
#pragma unroll
  for (int j = 0; j < 2; ++j) bfr[0][j] = *(const bf16x8*)(bp + (size_t)(j * 16) * KPAD);

  f32x4 acc[2];
#pragma unroll
  for (int j = 0; j < 2; ++j) acc[j] = f32x4{0.f, 0.f, 0.f, 0.f};

  for (int k0 = 0; k0 < KPAD; k0 += 64) {
#pragma unroll
    for (int ph = 0; ph < 2; ++ph) {
      const int cur = ph, nxt = ph ^ 1;
      const int kc = k0 + 32 * ph;
      const int kn = (kc + 32 == KPAD) ? 0 : kc + 32;
      af[nxt] = *(const bf16x8*)(ap + kn);
#pragma unroll
      for (int j = 0; j < 2; ++j)
        bfr[nxt][j] = *(const bf16x8*)(bp + (size_t)(j * 16) * KPAD + kn);
#pragma unroll
      for (int j = 0; j < 2; ++j) acc[j] = MFMA32(af[cur], bfr[cur][j], acc[j], 0, 0, 0);
    }
  }

  const int mr = m0 + wave * 16 + 4 * g;
  if constexpr (MODE == 2) {
    float* out = (float*)dstv;
#pragma unroll
    for (int j = 0; j < 2; ++j) {
      int col = n0 + j * 16 + li;
#pragma unroll
      for (int r = 0; r < 4; ++r) out[(size_t)(mr + r) * Nout + col] = acc[j][r];
    }
  } else if constexpr (MODE == 0) {
    unsigned short* out = (unsigned short*)dstv;
#pragma unroll
    for (int j = 0; j < 2; ++j) {
      int col = n0 + j * 16 + li;
      int h = col >> 6, d = col & 63;
#pragma unroll
      for (int r = 0; r < 4; ++r) {
        int m = mr + r;
        int b = m >> 11, seq = m & 2047;
        out[(((size_t)b * 9 + h) * 2048 + seq) * 64 + d] = f2bf(acc[j][r] * oscale);
      }
    }
  } else {
    unsigned short* out = (unsigned short*)dstv;
    int b = mr >> 11, seq0 = mr & 2047;
#pragma unroll
    for (int j = 0; j < 2; ++j) {
      int col = n0 + j * 16 + li;
      int h = col >> 6, d = col & 63;
      ushort4 pk = make_ushort4(f2bf(acc[j][0]), f2bf(acc[j][1]), f2bf(acc[j][2]), f2bf(acc[j][3]));
      *(ushort4*)(out + (((size_t)b * 9 + h) * 64 + d) * 2048 + seq0) = pk;
    }
  }
}

// ---------------- flash attention, split-KV ----------------
// grid (32, 9, 2*NS), 4 waves/block, wave owns 16 q-rows, KV stripe of 2048/NS.
// QK: S^T = K·Q^T via 16x16x32 (lane: q=li, kv=16t+4g+r).
// PV: out^T = V^T·P^T via 16x16x16_1k — S^T D-frag IS the B-operand (k=4g+r), no LDS.
// NS==1 writes aout directly; NS>1 writes fp32 partials (acc, m, l).
template <int NS>
__global__ __launch_bounds__(256) void k_attn(const unsigned short* __restrict__ qb,
                                              const unsigned short* __restrict__ kb,
                                              const unsigned short* __restrict__ vt,
                                              unsigned short* __restrict__ aout,
                                              float* __restrict__ pacc,
                                              float* __restrict__ pml) {
  constexpr int CH = 2048 / NS;
  constexpr int CHUNK = (32 * 9 * 2 * NS) / 8;
  int lin = blockIdx.x + 32 * (blockIdx.y + 9 * blockIdx.z);
  int nl = (lin & 7) * CHUNK + (lin >> 3);
  int bx = nl & 31;
  int rest = nl >> 5;
  int h = rest % 9;
  int z = rest / 9;
  int b = z / NS, sp = z - b * NS;

  const int wave = threadIdx.x >> 6, lane = threadIdx.x & 63;
  const int li = lane & 15, g = lane >> 4;
  const int n0 = bx * 64 + wave * 16;
  const int bh = b * 9 + h;

  const unsigned short* qp = qb + ((size_t)bh * 2048 + n0 + li) * 64 + g * 8;
  bf16x8 qf0 = *(const bf16x8*)qp;         // d = 8g+e   (scale pre-folded)
  bf16x8 qf1 = *(const bf16x8*)(qp + 32);  // d = 32+8g+e

  const unsigned short* kp = kb + ((size_t)bh * 2048 + sp * CH + li) * 64 + g * 8;
  const unsigned short* vp0 = vt + ((size_t)bh * 64 + li) * 2048 + sp * CH + 4 * g;
  const unsigned short* vp1 = vp0 + (size_t)16 * 2048;
  const unsigned short* vp2 = vp0 + (size_t)32 * 2048;
  const unsigned short* vp3 = vp0 + (size_t)48 * 2048;

  float m_run = -1e30f, l_run = 0.f;
  f32x4 acc[4];
#pragma unroll
  for (int t = 0; t < 4; ++t) acc[t] = f32x4{0.f, 0.f, 0.f, 0.f};

  for (int kv = 0; kv < CH; kv += 32) {
    // QK^T: s0 -> kv_local 0..15 (=4g+r), s1 -> 16..31
    f32x4 s0 = {0.f, 0.f, 0.f, 0.f}, s1 = {0.f, 0.f, 0.f, 0.f};
    s0 = MFMA32(*(const bf16x8*)kp, qf0, s0, 0, 0, 0);
    s0 = MFMA32(*(const bf16x8*)(kp + 32), qf1, s0, 0, 0, 0);
    s1 = MFMA32(*(const bf16x8*)(kp + 1024), qf0, s1, 0, 0, 0);
    s1 = MFMA32(*(const bf16x8*)(kp + 1056), qf1, s1, 0, 0, 0);
    kp += 32 * 64;

    float mx = fmaxf(fmaxf(fmaxf(s0[0], s0[1]), fmaxf(s0[2], s0[3])),
                     fmaxf(fmaxf(s1[0], s1[1]), fmaxf(s1[2], s1[3])));
    mx = fmaxf(mx, __shfl_xor(mx, 16));
    mx = fmaxf(mx, __shfl_xor(mx, 32));
    if (!__all(mx <= m_run + 8.f)) {  // defer-rescale (T13)
      float mn = fmaxf(m_run, mx);
      float corr = __builtin_amdgcn_exp2f(m_run - mn);
      l_run *= corr;
#pragma unroll
      for (int t = 0; t < 4; ++t) acc[t] *= corr;
      m_run = mn;
    }
    float e0[4], e1[4], ts = 0.f;
#pragma unroll
    for (int r = 0; r < 4; ++r) {
      e0[r] = __builtin_amdgcn_exp2f(s0[r] - m_run);
      e1[r] = __builtin_amdgcn_exp2f(s1[r] - m_run);
      ts += e0[r] + e1[r];
    }
    ts += __shfl_xor(ts, 16);
    ts += __shfl_xor(ts, 32);
    l_run += ts;

    short4v p0 = {(short)f2bf(e0[0]), (short)f2bf(e0[1]), (short)f2bf(e0[2]), (short)f2bf(e0[3])};
    short4v p1 = {(short)f2bf(e1[0]), (short)f2bf(e1[1]), (short)f2bf(e1[2]), (short)f2bf(e1[3])};

    // PV: acc[tt] covers d = 16tt+4g+r; A-frag = V^T rows (d=li), k=4g+e
    acc[0] = MFMA16K(*(const short4v*)(vp0 + kv), p0, acc[0], 0, 0, 0);
    acc[0] = MFMA16K(*(const short4v*)(vp0 + kv + 16), p1, acc[0], 0, 0, 0);
    acc[1] = MFMA16K(*(const short4v*)(vp1 + kv), p0, acc[1], 0, 0, 0);
    acc[1] = MFMA16K(*(const short4v*)(vp1 + kv + 16), p1, acc[1], 0, 0, 0);
    acc[2] = MFMA16K(*(const short4v*)(vp2 + kv), p0, acc[2], 0, 0, 0);
    acc[2] = MFMA16K(*(const short4v*)(vp2 + kv + 16), p1, acc[2], 0, 0, 0);
    acc[3] = MFMA16K(*(const short4v*)(vp3 + kv), p0, acc[3], 0, 0, 0);
    acc[3] = MFMA16K(*(const short4v*)(vp3 + kv + 16), p1, acc[3], 0, 0, 0);
  }

  if constexpr (NS == 1) {
    float inv = 1.f / l_run;
    unsigned short* orow = aout + ((size_t)(b * 2048) + n0 + li) * KPAD + h * 64;
#pragma unroll
    for (int t = 0; t < 4; ++t) {
      ushort4 pk = make_ushort4(f2bf(acc[t][0] * inv), f2bf(acc[t][1] * inv),
                                f2bf(acc[t][2] * inv), f2bf(acc[t][3] * inv));
      *(ushort4*)(orow + t * 16 + 4 * g) = pk;
    }
  } else {
    int tile = bh * 128 + (n0 >> 4);
    float* pa = pacc + ((size_t)tile * NS + sp) * 1024 + li * 64;
#pragma unroll
    for (int t = 0; t < 4; ++t) *(f32x4*)(pa + t * 16 + 4 * g) = acc[t];
    if (g == 0) {
      float2 st = make_float2(m_run, l_run);
      *(float2*)(pml + ((size_t)tile * NS + sp) * 32 + li * 2) = st;
    }
  }
}

// combine split-KV partials -> aout bf16
__global__ __launch_bounds__(256) void k_combine(const float* __restrict__ pacc,
                                                 const float* __restrict__ pml,
                                                 unsigned short* __restrict__ aout, int NS) {
  int tile = blockIdx.x;  // bh*128 + qt
  int bh = tile >> 7, qt = tile & 127;
  int b = bh / 9, h = bh - b * 9;
  int d = threadIdx.x & 63, q0 = threadIdx.x >> 6;
  for (int q = q0; q < 16; q += 4) {
    const float* ml = pml + (size_t)tile * NS * 32 + q * 2;
    float M = -1e30f;
    for (int sp = 0; sp < NS; ++sp) M = fmaxf(M, ml[sp * 32]);
    float num = 0.f, den = 0.f;
    const float* pa = pacc + (size_t)tile * NS * 1024 + q * 64 + d;
    for (int sp = 0; sp < NS; ++sp) {
      float w = __builtin_amdgcn_exp2f(ml[sp * 32] - M);
      den += w * ml[sp * 32 + 1];
      num += w * pa[(size_t)sp * 1024];
    }
    aout[((size_t)(b * 2048 + qt * 16 + q)) * KPAD + h * 64 + d] = f2bf(num / den);
  }
}

// ---------------- launch ----------------

extern "C" void kernel_launch(void* const* d_in, const int* in_sizes, int n_in,
                              void* d_out, int out_size, void* d_ws, size_t ws_size,
                              hipStream_t stream) {
  const float* x  = (const float*)d_in[0];
  const float* y  = (const float*)d_in[1];
  const float* cx = (const float*)d_in[2];
  const float* cy = (const float*)d_in[3];
  const float* Wq = (const float*)d_in[4];
  const float* Wk = (const float*)d_in[5];
  const float* Wv = (const float*)d_in[6];
  const float* Wo = (const float*)d_in[7];
  const float* cs = (const float*)d_in[8];

  char* w = (char*)d_ws;
  auto take = [&](size_t bytes) {
    char* p = w;
    w += (bytes + 255) & ~(size_t)255;
    return p;
  };
  unsigned short* posed_x = (unsigned short*)take((size_t)4096 * KPAD * 2);
  unsigned short* posed_y = (unsigned short*)take((size_t)4096 * KPAD * 2);
  unsigned short* wqT = (unsigned short*)take((size_t)512 * KPAD * 2);
  unsigned short* wkT = (unsigned short*)take((size_t)512 * KPAD * 2);
  unsigned short* wvT = (unsigned short*)take((size_t)576 * KPAD * 2);
  unsigned short* woT = (unsigned short*)take((size_t)512 * KPAD * 2);
  unsigned short* qbuf = (unsigned short*)take((size_t)2 * 9 * 2048 * 64 * 2);
  unsigned short* kbuf = (unsigned short*)take((size_t)2 * 9 * 2048 * 64 * 2);
  unsigned short* vtb  = (unsigned short*)take((size_t)2 * 9 * 64 * 2048 * 2);
  unsigned short* aout = (unsigned short*)take((size_t)4096 * KPAD * 2);

  size_t base_used = (size_t)(w - (char*)d_ws);
  auto fits = [&](int ns) {
    return base_used + (size_t)2304 * ns * (1024 + 32) * 4 + 1024 <= ws_size;
  };
  int NS = fits(4) ? 4 : (fits(2) ? 2 : 1);
  float* pacc = nullptr;
  float* pml = nullptr;
  if (NS > 1) {
    pacc = (float*)take((size_t)2304 * NS * 1024 * 4);
    pml  = (float*)take((size_t)2304 * NS * 32 * 4);
  }

  k_pack_posed<<<(4096 * KPAD + 255) / 256, 256, 0, stream>>>(x, cx, posed_x, 4096);
  k_pack_posed<<<(4096 * KPAD + 255) / 256, 256, 0, stream>>>(y, cy, posed_y, 4096);
  k_pack_wT<<<(512 * KPAD + 255) / 256, 256, 0, stream>>>(Wq, wqT, 515, 512);
  k_pack_wT<<<(512 * KPAD + 255) / 256, 256, 0, stream>>>(Wk, wkT, 515, 512);
  k_pack_wT<<<(576 * KPAD + 255) / 256, 256, 0, stream>>>(Wv, wvT, 515, 576);
  k_pack_wT<<<(512 * KPAD + 255) / 256, 256, 0, stream>>>(Wo, woT, 576, 512);
  k_pack_ch<<<(4096 * 64 + 255) / 256, 256, 0, stream>>>(cx, qbuf, cs);
  k_pack_ch<<<(4096 * 64 + 255) / 256, 256, 0, stream>>>(cy, kbuf, nullptr);

  const float qsc = 0.125f * LOG2E;
  dim3 gq(64, 16);
  k_gemm<0><<<gq, 256, 0, stream>>>(posed_x, wqT, qbuf, 512, qsc);
  k_gemm<0><<<gq, 256, 0, stream>>>(posed_y, wkT, kbuf, 512, 1.f);
  dim3 gv(64, 18);
  k_gemm<1><<<gv, 256, 0, stream>>>(posed_y, wvT, vtb, 576, 1.f);

  dim3 ga(32, 9, 2 * NS);
  if (NS == 4)      k_attn<4><<<ga, 256, 0, stream>>>(qbuf, kbuf, vtb, aout, pacc, pml);
  else if (NS == 2) k_attn<2><<<ga, 256, 0, stream>>>(qbuf, kbuf, vtb, aout, pacc, pml);
  else              k_attn<1><<<ga, 256, 0, stream>>>(qbuf, kbuf, vtb, aout, pacc, pml);
  if (NS > 1) k_combine<<<2304, 256, 0, stream>>>(pacc, pml, aout, NS);

  dim3 go(64, 16);
  k_gemm<2><<<go, 256, 0, stream>>>(aout, woT, d_out, 512, 1.f);
}

// Round 4
// 130.623 us; speedup vs baseline: 2.8628x; 2.8628x over previous
//
#include <hip/hip_runtime.h>

typedef __bf16 bf16x8 __attribute__((ext_vector_type(8)));
typedef short short4v __attribute__((ext_vector_type(4)));
typedef float f32x4 __attribute__((ext_vector_type(4)));

#define MFMA32 __builtin_amdgcn_mfma_f32_16x16x32_bf16
#define MFMA16K __builtin_amdgcn_mfma_f32_16x16x16bf16_1k

#define KPAD 576
#define LOG2E 1.44269504f

__device__ __forceinline__ unsigned short f2bf(float f) {
  unsigned u = __float_as_uint(f);
  u += 0x7FFFu + ((u >> 16) & 1u);
  return (unsigned short)(u >> 16);
}

__device__ __forceinline__ void gl_lds16(const void* g, void* l) {
  __builtin_amdgcn_global_load_lds((const __attribute__((address_space(1))) unsigned int*)g,
                                   (__attribute__((address_space(3))) unsigned int*)l, 16, 0, 0);
}

// ---------------- pack kernels ----------------

__global__ void k_pack_posed(const float* __restrict__ feat, const float* __restrict__ coord,
                             unsigned short* __restrict__ dst, int rows) {
  int i = blockIdx.x * 256 + threadIdx.x;
  int total = rows * KPAD;
  if (i >= total) return;
  int r = i / KPAD, c = i - r * KPAD;
  float v = 0.f;
  if (c < 512) v = feat[(size_t)r * 512 + c];
  else if (c < 515) v = coord[(size_t)r * 3 + (c - 512)];
  dst[i] = f2bf(v);
}

__global__ void k_pack_wT(const float* __restrict__ w, unsigned short* __restrict__ dst,
                          int kin, int nout) {
  int i = blockIdx.x * 256 + threadIdx.x;
  if (i >= nout * KPAD) return;
  int n = i / KPAD, kc = i - n * KPAD;
  float v = (kc < kin) ? w[(size_t)kc * nout + n] : 0.f;
  dst[i] = f2bf(v);
}

// coord head (h=8) of q/k buffer; cs!=null -> fold cscale*log2e (q side)
__global__ void k_pack_ch(const float* __restrict__ coord, unsigned short* __restrict__ buf,
                          const float* __restrict__ cs) {
  int i = blockIdx.x * 256 + threadIdx.x;
  if (i >= 4096 * 64) return;
  int row = i >> 6, d = i & 63;
  int b = row >> 11, n = row & 2047;
  float sc = cs ? cs[0] * LOG2E : 1.f;
  float v = (d < 3) ? coord[(size_t)row * 3 + d] * sc : 0.f;
  buf[(((size_t)b * 9 + 8) * 2048 + n) * 64 + d] = f2bf(v);
}

// ---------------- GEMM: C[m,n] = sum_k A[m,k]*BT[n,k], K=KPAD ----------------
// 64x64 tile, 4 waves (wave: 16 rows x 64 cols). B tile (64n x 32k) LDS-staged
// per k-step (shared by all 4 waves, XOR-swizzled), double-buffered 2-phase.
// A direct global, register-prefetched one step ahead.
template <int MODE>
__global__ __launch_bounds__(256) void k_gemm(const unsigned short* __restrict__ A,
                                              const unsigned short* __restrict__ BT,
                                              void* __restrict__ dstv, int Nout, float oscale) {
  __shared__ unsigned short bs[2][64 * 32];  // 4KB per buffer
  const int m0 = blockIdx.x * 64;
  const int n0 = blockIdx.y * 64;
  const int wave = threadIdx.x >> 6;
  const int lane = threadIdx.x & 63;
  const int li = lane & 15, g = lane >> 4;

  // stage B tile for k-step s into bs[bufi]; chunk f = wave*64+lane (16B each)
  auto stageB = [&](int bufi, int s) {
    int f = wave * 64 + lane;
    int row = f >> 2, c = f & 3, sc = c ^ (row & 3);
    const unsigned short* src = BT + (size_t)(n0 + row) * KPAD + s * 32 + sc * 8;
    gl_lds16(src, &bs[bufi][(wave * 64) * 8]);
  };

  const unsigned short* ap = A + (size_t)(m0 + wave * 16 + li) * KPAD + g * 8;

  f32x4 acc[4];
#pragma unroll
  for (int j = 0; j < 4; ++j) acc[j] = f32x4{0.f, 0.f, 0.f, 0.f};

  stageB(0, 0);
  bf16x8 af = *(const bf16x8*)ap;
  asm volatile("s_waitcnt vmcnt(0)" ::: "memory");
  __syncthreads();

  for (int s = 0; s < KPAD / 32; ++s) {
    const int cb = s & 1;
    bf16x8 afn;
    if (s + 1 < KPAD / 32) {
      stageB(cb ^ 1, s + 1);
      afn = *(const bf16x8*)(ap + (s + 1) * 32);
    }
    const unsigned short* bb = &bs[cb][0];
#pragma unroll
    for (int j = 0; j < 4; ++j) {
      int row = j * 16 + li;
      bf16x8 bfrag = *(const bf16x8*)(bb + row * 32 + ((g ^ (row & 3)) << 3));
      acc[j] = MFMA32(af, bfrag, acc[j], 0, 0, 0);
    }
    af = afn;
    __syncthreads();
  }

  const int mr = m0 + wave * 16 + 4 * g;
  if constexpr (MODE == 2) {
    float* out = (float*)dstv;
#pragma unroll
    for (int j = 0; j < 4; ++j) {
      int col = n0 + j * 16 + li;
#pragma unroll
      for (int r = 0; r < 4; ++r) out[(size_t)(mr + r) * Nout + col] = acc[j][r];
    }
  } else if constexpr (MODE == 0) {
    unsigned short* out = (unsigned short*)dstv;
#pragma unroll
    for (int j = 0; j < 4; ++j) {
      int col = n0 + j * 16 + li;
      int h = col >> 6, d = col & 63;
#pragma unroll
      for (int r = 0; r < 4; ++r) {
        int m = mr + r;
        int b = m >> 11, seq = m & 2047;
        out[(((size_t)b * 9 + h) * 2048 + seq) * 64 + d] = f2bf(acc[j][r] * oscale);
      }
    }
  } else {
    unsigned short* out = (unsigned short*)dstv;
    int b = mr >> 11, seq0 = mr & 2047;
#pragma unroll
    for (int j = 0; j < 4; ++j) {
      int col = n0 + j * 16 + li;
      int h = col >> 6, d = col & 63;
      ushort4 pk = make_ushort4(f2bf(acc[j][0]), f2bf(acc[j][1]), f2bf(acc[j][2]), f2bf(acc[j][3]));
      *(ushort4*)(out + (((size_t)b * 9 + h) * 64 + d) * 2048 + seq0) = pk;
    }
  }
}

// ---------------- flash attention, LDS-staged K/V ----------------
// Block = 128 q-rows (4 waves x 2 groups of 16), KV stripe = 2048/NS, tiles of 64.
// K tile [64kv][64d] and V^T tile [64d][64kv] staged to LDS via global_load_lds
// (linear dest, source chunk-XOR-swizzled by row&7), double-buffered 2-phase.
// QK: S^T = K·Q^T (MFMA32, A=K from LDS, B=Q regs). PV: out^T = V^T·P^T
// (MFMA16K, A=V^T from LDS, B=P in regs straight from S^T fragment).
template <int NS>
__global__ __launch_bounds__(256) void k_attn(const unsigned short* __restrict__ qb,
                                              const unsigned short* __restrict__ kb,
                                              const unsigned short* __restrict__ vt,
                                              unsigned short* __restrict__ aout,
                                              float* __restrict__ pacc,
                                              float* __restrict__ pml) {
  constexpr int CH = 2048 / NS;
  constexpr int NT = CH / 64;
  constexpr int NBLK = 16 * 9 * 2 * NS;
  __shared__ unsigned short kt[2][4096];   // [buf][64 kv][64 d], swizzled
  __shared__ unsigned short vtl[2][4096];  // [buf][64 d][64 kv], swizzled

  int lin = blockIdx.x + 16 * (blockIdx.y + 9 * blockIdx.z);
  int nl = (lin & 7) * (NBLK / 8) + (lin >> 3);
  int bx = nl & 15;
  int rest = nl >> 4;
  int h = rest % 9;
  int z = rest / 9;
  int b = z / NS, sp = z - b * NS;

  const int wave = threadIdx.x >> 6, lane = threadIdx.x & 63;
  const int li = lane & 15, g = lane >> 4;
  const int bh = b * 9 + h;
  const int kvbase = sp * CH;

  // Q fragments: 2 groups of 16 rows
  bf16x8 qf[2][2];
#pragma unroll
  for (int u = 0; u < 2; ++u) {
    const unsigned short* qp =
        qb + ((size_t)bh * 2048 + bx * 128 + wave * 32 + u * 16 + li) * 64 + g * 8;
    qf[u][0] = *(const bf16x8*)qp;
    qf[u][1] = *(const bf16x8*)(qp + 32);
  }

  auto stage = [&](int bufi, int tile) {
    const int kv0 = kvbase + tile * 64;
#pragma unroll
    for (int rd = 0; rd < 2; ++rd) {
      int f = rd * 256 + wave * 64 + lane;
      int row = f >> 3, c = f & 7, sc = c ^ (row & 7);
      const unsigned short* ks = kb + ((size_t)bh * 2048 + kv0 + row) * 64 + sc * 8;
      gl_lds16(ks, &kt[bufi][(rd * 256 + wave * 64) * 8]);
      const unsigned short* vs = vt + ((size_t)bh * 64 + row) * 2048 + kv0 + sc * 8;
      gl_lds16(vs, &vtl[bufi][(rd * 256 + wave * 64) * 8]);
    }
  };

  float m_run[2] = {-1e30f, -1e30f}, l_run[2] = {0.f, 0.f};
  f32x4 acc[2][4];
#pragma unroll
  for (int u = 0; u < 2; ++u)
#pragma unroll
    for (int t = 0; t < 4; ++t) acc[u][t] = f32x4{0.f, 0.f, 0.f, 0.f};

  stage(0, 0);
  asm volatile("s_waitcnt vmcnt(0)" ::: "memory");
  __syncthreads();

  for (int t = 0; t < NT; ++t) {
    const int cb = t & 1;
    if (t + 1 < NT) stage(cb ^ 1, t + 1);

    const unsigned short* kl = &kt[cb][0];
    const unsigned short* vl = &vtl[cb][0];

    // K fragments (shared by both q-groups)
    bf16x8 kA[4][2];
#pragma unroll
    for (int tt = 0; tt < 4; ++tt) {
      int r = tt * 16 + li, swz = r & 7;
      kA[tt][0] = *(const bf16x8*)(kl + r * 64 + ((g ^ swz) << 3));
      kA[tt][1] = *(const bf16x8*)(kl + r * 64 + (((4 + g) ^ swz) << 3));
    }

    // QK^T for both groups: s[u][tt] covers kv_local = 16tt + 4g + r
    f32x4 s[2][4];
#pragma unroll
    for (int u = 0; u < 2; ++u)
#pragma unroll
      for (int tt = 0; tt < 4; ++tt) {
        f32x4 sv = {0.f, 0.f, 0.f, 0.f};
        sv = MFMA32(kA[tt][0], qf[u][0], sv, 0, 0, 0);
        sv = MFMA32(kA[tt][1], qf[u][1], sv, 0, 0, 0);
        s[u][tt] = sv;
      }

    // online softmax per group (log2 domain; scale pre-folded into Q)
    short4v p[2][4];
#pragma unroll
    for (int u = 0; u < 2; ++u) {
      float mx = -1e30f;
#pragma unroll
      for (int tt = 0; tt < 4; ++tt)
#pragma unroll
        for (int r = 0; r < 4; ++r) mx = fmaxf(mx, s[u][tt][r]);
      mx = fmaxf(mx, __shfl_xor(mx, 16));
      mx = fmaxf(mx, __shfl_xor(mx, 32));
      if (!__all(mx <= m_run[u] + 8.f)) {  // defer-rescale (T13)
        float mn = fmaxf(m_run[u], mx);
        float corr = __builtin_amdgcn_exp2f(m_run[u] - mn);
        l_run[u] *= corr;
#pragma unroll
        for (int tt = 0; tt < 4; ++tt) acc[u][tt] *= corr;
        m_run[u] = mn;
      }
      float ts = 0.f;
#pragma unroll
      for (int tt = 0; tt < 4; ++tt) {
        float e0 = __builtin_amdgcn_exp2f(s[u][tt][0] - m_run[u]);
        float e1 = __builtin_amdgcn_exp2f(s[u][tt][1] - m_run[u]);
        float e2 = __builtin_amdgcn_exp2f(s[u][tt][2] - m_run[u]);
        float e3 = __builtin_amdgcn_exp2f(s[u][tt][3] - m_run[u]);
        ts += (e0 + e1) + (e2 + e3);
        p[u][tt] = short4v{(short)f2bf(e0), (short)f2bf(e1), (short)f2bf(e2), (short)f2bf(e3)};
      }
      ts += __shfl_xor(ts, 16);
      ts += __shfl_xor(ts, 32);
      l_run[u] += ts;
    }

    // V^T fragments + PV
#pragma unroll
    for (int dd = 0; dd < 4; ++dd) {
      int r = dd * 16 + li, swz = r & 7;
      short4v vA[4];
#pragma unroll
      for (int sl = 0; sl < 4; ++sl) {
        int chunk = (2 * sl + (g >> 1)) ^ swz;
        vA[sl] = *(const short4v*)(vl + r * 64 + (chunk << 3) + ((g & 1) << 2));
      }
#pragma unroll
      for (int sl = 0; sl < 4; ++sl) {
        acc[0][dd] = MFMA16K(vA[sl], p[0][sl], acc[0][dd], 0, 0, 0);
        acc[1][dd] = MFMA16K(vA[sl], p[1][sl], acc[1][dd], 0, 0, 0);
      }
    }
    __syncthreads();
  }

  if constexpr (NS == 1) {
#pragma unroll
    for (int u = 0; u < 2; ++u) {
      float inv = 1.f / l_run[u];
      unsigned short* orow =
          aout + ((size_t)(b * 2048 + bx * 128 + wave * 32 + u * 16 + li)) * KPAD + h * 64;
#pragma unroll
      for (int t = 0; t < 4; ++t) {
        ushort4 pk = make_ushort4(f2bf(acc[u][t][0] * inv), f2bf(acc[u][t][1] * inv),
                                  f2bf(acc[u][t][2] * inv), f2bf(acc[u][t][3] * inv));
        *(ushort4*)(orow + t * 16 + 4 * g) = pk;
      }
    }
  } else {
#pragma unroll
    for (int u = 0; u < 2; ++u) {
      int tile = bh * 128 + bx * 8 + wave * 2 + u;
      float* pa = pacc + ((size_t)tile * NS + sp) * 1024 + li * 64;
#pragma unroll
      for (int t = 0; t < 4; ++t) *(f32x4*)(pa + t * 16 + 4 * g) = acc[u][t];
      if (g == 0) {
        float2 st = make_float2(m_run[u], l_run[u]);
        *(float2*)(pml + ((size_t)tile * NS + sp) * 32 + li * 2) = st;
      }
    }
  }
}

// combine split-KV partials -> aout bf16
__global__ __launch_bounds__(256) void k_combine(const float* __restrict__ pacc,
                                                 const float* __restrict__ pml,
                                                 unsigned short* __restrict__ aout, int NS) {
  int tile = blockIdx.x;  // bh*128 + qt
  int bh = tile >> 7, qt = tile & 127;
  int b = bh / 9, h = bh - b * 9;
  int d = threadIdx.x & 63, q0 = threadIdx.x >> 6;
  for (int q = q0; q < 16; q += 4) {
    const float* ml = pml + (size_t)tile * NS * 32 + q * 2;
    float M = -1e30f;
    for (int sp = 0; sp < NS; ++sp) M = fmaxf(M, ml[sp * 32]);
    float num = 0.f, den = 0.f;
    const float* pa = pacc + (size_t)tile * NS * 1024 + q * 64 + d;
    for (int sp = 0; sp < NS; ++sp) {
      float w = __builtin_amdgcn_exp2f(ml[sp * 32] - M);
      den += w * ml[sp * 32 + 1];
      num += w * pa[(size_t)sp * 1024];
    }
    aout[((size_t)(b * 2048 + qt * 16 + q)) * KPAD + h * 64 + d] = f2bf(num / den);
  }
}

// ---------------- launch ----------------

extern "C" void kernel_launch(void* const* d_in, const int* in_sizes, int n_in,
                              void* d_out, int out_size, void* d_ws, size_t ws_size,
                              hipStream_t stream) {
  const float* x  = (const float*)d_in[0];
  const float* y  = (const float*)d_in[1];
  const float* cx = (const float*)d_in[2];
  const float* cy = (const float*)d_in[3];
  const float* Wq = (const float*)d_in[4];
  const float* Wk = (const float*)d_in[5];
  const float* Wv = (const float*)d_in[6];
  const float* Wo = (const float*)d_in[7];
  const float* cs = (const float*)d_in[8];

  char* w = (char*)d_ws;
  auto take = [&](size_t bytes) {
    char* p = w;
    w += (bytes + 255) & ~(size_t)255;
    return p;
  };
  unsigned short* posed_x = (unsigned short*)take((size_t)4096 * KPAD * 2);
  unsigned short* posed_y = (unsigned short*)take((size_t)4096 * KPAD * 2);
  unsigned short* wqT = (unsigned short*)take((size_t)512 * KPAD * 2);
  unsigned short* wkT = (unsigned short*)take((size_t)512 * KPAD * 2);
  unsigned short* wvT = (unsigned short*)take((size_t)576 * KPAD * 2);
  unsigned short* woT = (unsigned short*)take((size_t)512 * KPAD * 2);
  unsigned short* qbuf = (unsigned short*)take((size_t)2 * 9 * 2048 * 64 * 2);
  unsigned short* kbuf = (unsigned short*)take((size_t)2 * 9 * 2048 * 64 * 2);
  unsigned short* vtb  = (unsigned short*)take((size_t)2 * 9 * 64 * 2048 * 2);
  unsigned short* aout = (unsigned short*)take((size_t)4096 * KPAD * 2);

  size_t base_used = (size_t)(w - (char*)d_ws);
  auto fits = [&](int ns) {
    return base_used + (size_t)2304 * ns * (1024 + 32) * 4 + 1024 <= ws_size;
  };
  int NS = fits(2) ? 2 : 1;
  float* pacc = nullptr;
  float* pml = nullptr;
  if (NS > 1) {
    pacc = (float*)take((size_t)2304 * NS * 1024 * 4);
    pml  = (float*)take((size_t)2304 * NS * 32 * 4);
  }

  k_pack_posed<<<(4096 * KPAD + 255) / 256, 256, 0, stream>>>(x, cx, posed_x, 4096);
  k_pack_posed<<<(4096 * KPAD + 255) / 256, 256, 0, stream>>>(y, cy, posed_y, 4096);
  k_pack_wT<<<(512 * KPAD + 255) / 256, 256, 0, stream>>>(Wq, wqT, 515, 512);
  k_pack_wT<<<(512 * KPAD + 255) / 256, 256, 0, stream>>>(Wk, wkT, 515, 512);
  k_pack_wT<<<(576 * KPAD + 255) / 256, 256, 0, stream>>>(Wv, wvT, 515, 576);
  k_pack_wT<<<(512 * KPAD + 255) / 256, 256, 0, stream>>>(Wo, woT, 576, 512);
  k_pack_ch<<<(4096 * 64 + 255) / 256, 256, 0, stream>>>(cx, qbuf, cs);
  k_pack_ch<<<(4096 * 64 + 255) / 256, 256, 0, stream>>>(cy, kbuf, nullptr);

  const float qsc = 0.125f * LOG2E;
  dim3 gq(64, 8);
  k_gemm<0><<<gq, 256, 0, stream>>>(posed_x, wqT, qbuf, 512, qsc);
  k_gemm<0><<<gq, 256, 0, stream>>>(posed_y, wkT, kbuf, 512, 1.f);
  dim3 gv(64, 9);
  k_gemm<1><<<gv, 256, 0, stream>>>(posed_y, wvT, vtb, 576, 1.f);

  dim3 ga(16, 9, 2 * NS);
  if (NS == 2) k_attn<2><<<ga, 256, 0, stream>>>(qbuf, kbuf, vtb, aout, pacc, pml);
  else         k_attn<1><<<ga, 256, 0, stream>>>(qbuf, kbuf, vtb, aout, pacc, pml);
  if (NS > 1) k_combine<<<2304, 256, 0, stream>>>(pacc, pml, aout, NS);

  dim3 go(64, 8);
  k_gemm<2><<<go, 256, 0, stream>>>(aout, woT, d_out, 512, 1.f);
}

// Round 5
// 114.399 us; speedup vs baseline: 3.2688x; 1.1418x over previous
//
#include <hip/hip_runtime.h>

typedef __bf16 bf16x8 __attribute__((ext_vector_type(8)));
typedef short short4v __attribute__((ext_vector_type(4)));
typedef short short8v __attribute__((ext_vector_type(8)));
typedef float f32x4 __attribute__((ext_vector_type(4)));

#define MFMA32 __builtin_amdgcn_mfma_f32_16x16x32_bf16
#define MFMA16K __builtin_amdgcn_mfma_f32_16x16x16bf16_1k

#define KPAD 576
#define LOG2E 1.44269504f

__device__ __forceinline__ unsigned short f2bf(float f) {
  unsigned u = __float_as_uint(f);
  u += 0x7FFFu + ((u >> 16) & 1u);
  return (unsigned short)(u >> 16);
}

__device__ __forceinline__ unsigned cvtpk_bf16(float a, float b) {
  unsigned r;
  asm("v_cvt_pk_bf16_f32 %0, %1, %2" : "=v"(r) : "v"(a), "v"(b));
  return r;  // lo = bf16(a), hi = bf16(b)
}

__device__ __forceinline__ short4v pack_bf16x4(float e0, float e1, float e2, float e3) {
  union { unsigned u[2]; short4v s; } pu;
  pu.u[0] = cvtpk_bf16(e0, e1);
  pu.u[1] = cvtpk_bf16(e2, e3);
  return pu.s;
}

__device__ __forceinline__ void gl_lds16(const void* g, void* l) {
  __builtin_amdgcn_global_load_lds((const __attribute__((address_space(1))) unsigned int*)g,
                                   (__attribute__((address_space(3))) unsigned int*)l, 16, 0, 0);
}

// ---------------- pack kernels ----------------

// posed = concat(feat[rows,512], coord[rows,3]) -> bf16 [rows, 576], zero-padded
__global__ void k_pack_posed(const float* __restrict__ feat, const float* __restrict__ coord,
                             unsigned short* __restrict__ dst, int rows) {
  int i = blockIdx.x * 256 + threadIdx.x;  // groups of 4 cols
  if (i >= rows * (KPAD / 4)) return;
  int r = i / (KPAD / 4), c = (i - r * (KPAD / 4)) * 4;
  float4 v = {0.f, 0.f, 0.f, 0.f};
  if (c < 512) v = *(const float4*)(feat + (size_t)r * 512 + c);
  else if (c == 512) {
    v.x = coord[(size_t)r * 3];
    v.y = coord[(size_t)r * 3 + 1];
    v.z = coord[(size_t)r * 3 + 2];
  }
  ushort4 o = make_ushort4(f2bf(v.x), f2bf(v.y), f2bf(v.z), f2bf(v.w));
  *(ushort4*)(dst + (size_t)i * 4) = o;
}

// dst[n, kc] = (kc < kin) ? w[kc, n] : 0 ; LDS tile transpose, coalesced both sides
__global__ void k_pack_wT(const float* __restrict__ w, unsigned short* __restrict__ dst,
                          int kin, int nout) {
  __shared__ unsigned short tile[32][33];
  int kc0 = blockIdx.x * 32, n0 = blockIdx.y * 32;
  int tx = threadIdx.x & 31, ty = threadIdx.x >> 5;  // 32 x 8
#pragma unroll
  for (int it = 0; it < 4; ++it) {
    int kc = kc0 + ty + it * 8;
    float v = (kc < kin) ? w[(size_t)kc * nout + n0 + tx] : 0.f;
    tile[ty + it * 8][tx] = f2bf(v);
  }
  __syncthreads();
#pragma unroll
  for (int it = 0; it < 4; ++it) {
    int n = n0 + ty + it * 8;
    dst[(size_t)n * KPAD + kc0 + tx] = tile[tx][ty + it * 8];
  }
}

// coord head (h=8) of q/k buffer; cs!=null -> fold cscale*log2e (q side)
__global__ void k_pack_ch(const float* __restrict__ coord, unsigned short* __restrict__ buf,
                          const float* __restrict__ cs) {
  int i = blockIdx.x * 256 + threadIdx.x;  // 4096 rows * 16 groups of 4
  if (i >= 4096 * 16) return;
  int row = i >> 4, d4 = (i & 15) * 4;
  int b = row >> 11, n = row & 2047;
  ushort4 o = make_ushort4(0, 0, 0, 0);
  if (d4 == 0) {
    float sc = cs ? cs[0] * LOG2E : 1.f;
    o.x = f2bf(coord[(size_t)row * 3] * sc);
    o.y = f2bf(coord[(size_t)row * 3 + 1] * sc);
    o.z = f2bf(coord[(size_t)row * 3 + 2] * sc);
  }
  *(ushort4*)(buf + (((size_t)b * 9 + 8) * 2048 + n) * 64 + d4) = o;
}

// ---------------- GEMM: C[m,n] = sum_k A[m,k]*BT[n,k], K=KPAD ----------------
// 64x64 tile, 8 waves (wave: 16 rows x 32 cols), A+B LDS-staged (chunk-XOR swizzle,
// linear dest / pre-swizzled source), BK=64, double-buffered.
// MODE 0: bf16 -> q/k layout  dst[((b*9+h)*2048+seq)*64+d], col=(h*64+d), *oscale
// MODE 1: bf16 -> vT PERMUTED layout (within 64-kv tile: n = g*16+sl*4+r)
// MODE 2: f32 row-major       dst[m*Nout+col]
template <int MODE>
__global__ __launch_bounds__(512) void k_gemm(const unsigned short* __restrict__ A,
                                              const unsigned short* __restrict__ BT,
                                              void* __restrict__ dstv, int Nout, float oscale) {
  __shared__ unsigned short smem[2][8192];  // [buf][A 4096 | B 4096]
  const int m0 = blockIdx.x * 64;
  const int n0 = blockIdx.y * 64;
  const int tid = threadIdx.x;
  const int wave = tid >> 6, lane = tid & 63;
  const int li = lane & 15, g = lane >> 4;
  const int wm = (wave & 3) * 16;
  const int wn = (wave >> 2) * 32;
  const int swz = li & 7;

  const int srow = tid >> 3, sc = (tid & 7) ^ (srow & 7);
  const unsigned short* asrc = A + (size_t)(m0 + srow) * KPAD + sc * 8;
  const unsigned short* bsrc = BT + (size_t)(n0 + srow) * KPAD + sc * 8;

  auto stg = [&](int buf, int s) {
    gl_lds16(asrc + s * 64, &smem[buf][wave * 512]);
    gl_lds16(bsrc + s * 64, &smem[buf][4096 + wave * 512]);
  };

  f32x4 acc[2];
#pragma unroll
  for (int j = 0; j < 2; ++j) acc[j] = f32x4{0.f, 0.f, 0.f, 0.f};

  stg(0, 0);
  asm volatile("s_waitcnt vmcnt(0)" ::: "memory");
  __syncthreads();

  constexpr int NSTEP = KPAD / 64;  // 9
  for (int s = 0; s < NSTEP; ++s) {
    const int cb = s & 1;
    if (s + 1 < NSTEP) stg(cb ^ 1, s + 1);
    const unsigned short* sa = &smem[cb][0];
    const unsigned short* sb = &smem[cb][4096];
#pragma unroll
    for (int hh = 0; hh < 2; ++hh) {
      bf16x8 af = *(const bf16x8*)(sa + (wm + li) * 64 + (((hh * 4 + g) ^ swz) << 3));
#pragma unroll
      for (int j = 0; j < 2; ++j) {
        int row = wn + j * 16 + li;
        bf16x8 bfr = *(const bf16x8*)(sb + row * 64 + (((hh * 4 + g) ^ swz) << 3));
        acc[j] = MFMA32(af, bfr, acc[j], 0, 0, 0);
      }
    }
    __syncthreads();
  }

  const int mr = m0 + wm + 4 * g;
  if constexpr (MODE == 2) {
    float* out = (float*)dstv;
#pragma unroll
    for (int j = 0; j < 2; ++j) {
      int col = n0 + wn + j * 16 + li;
#pragma unroll
      for (int r = 0; r < 4; ++r) out[(size_t)(mr + r) * Nout + col] = acc[j][r];
    }
  } else if constexpr (MODE == 0) {
    unsigned short* out = (unsigned short*)dstv;
#pragma unroll
    for (int j = 0; j < 2; ++j) {
      int col = n0 + wn + j * 16 + li;
      int h = col >> 6, d = col & 63;
#pragma unroll
      for (int r = 0; r < 4; ++r) {
        int m = mr + r;
        int b = m >> 11, seq = m & 2047;
        out[(((size_t)b * 9 + h) * 2048 + seq) * 64 + d] = f2bf(acc[j][r] * oscale);
      }
    }
  } else {
    unsigned short* out = (unsigned short*)dstv;
    int b = mr >> 11, seq0 = mr & 2047;  // r=0..3 consecutive kv
    int c0 = seq0 & 63;
    int npos = (seq0 & ~63) + ((c0 >> 2) & 3) * 16 + (c0 >> 4) * 4;  // permuted
#pragma unroll
    for (int j = 0; j < 2; ++j) {
      int col = n0 + wn + j * 16 + li;
      int h = col >> 6, d = col & 63;
      ushort4 pk = make_ushort4(f2bf(acc[j][0]), f2bf(acc[j][1]), f2bf(acc[j][2]), f2bf(acc[j][3]));
      *(ushort4*)(out + (((size_t)b * 9 + h) * 64 + d) * 2048 + npos) = pk;
    }
  }
}

// ---------------- flash attention, LDS-staged K/V, split-KV ----------------
// Block = 128 q-rows (4 waves x 2 groups of 16), KV stripe 2048/NS, 64-kv tiles.
// K [64kv][64d] and V^T [64d][64kv-permuted] staged via global_load_lds
// (linear dest, chunk-XOR source), double-buffered; tile loop unrolled x2 so
// buffer offsets are immediates. Softmax: defer-max (no per-tile shfl reduce),
// per-lane l partials, cvt_pk P conversion. PV via 16x16x16 (P stays in regs).
template <int NS>
__global__ __launch_bounds__(256) void k_attn(const unsigned short* __restrict__ qb,
                                              const unsigned short* __restrict__ kb,
                                              const unsigned short* __restrict__ vt,
                                              unsigned short* __restrict__ aout,
                                              float* __restrict__ pacc,
                                              float* __restrict__ pml) {
  constexpr int CH = 2048 / NS;
  constexpr int NT = CH / 64;
  constexpr int NBLK = 16 * 9 * 2 * NS;
  __shared__ unsigned short smem[16384];  // [0,8192): K dbuf ; [8192,16384): V dbuf

  int lin = blockIdx.x + 16 * (blockIdx.y + 9 * blockIdx.z);
  int nl = (lin & 7) * (NBLK / 8) + (lin >> 3);
  int bx = nl & 15;
  int rest = nl >> 4;
  int h = rest % 9;
  int z = rest / 9;
  int b = z / NS, sp = z - b * NS;

  const int wave = threadIdx.x >> 6, lane = threadIdx.x & 63;
  const int li = lane & 15, g = lane >> 4;
  const int bh = b * 9 + h;
  const int kvbase = sp * CH;
  const int swz = li & 7;

  // Q fragments (scale pre-folded): 2 groups of 16 rows
  bf16x8 qf[2][2];
#pragma unroll
  for (int u = 0; u < 2; ++u) {
    const unsigned short* qp =
        qb + ((size_t)bh * 2048 + bx * 128 + wave * 32 + u * 16 + li) * 64 + g * 8;
    qf[u][0] = *(const bf16x8*)qp;
    qf[u][1] = *(const bf16x8*)(qp + 32);
  }

  // persistent staging source pointers (row = tid>>3 in 0..31, +32 via offset)
  const int srow = threadIdx.x >> 3;
  const int ssc = (threadIdx.x & 7) ^ (srow & 7);
  const unsigned short* ksrc = kb + ((size_t)bh * 2048 + kvbase + srow) * 64 + ssc * 8;
  const unsigned short* vsrc = vt + ((size_t)bh * 64 + srow) * 2048 + kvbase + ssc * 8;

  // per-lane LDS frag base pointers (ushort units)
  const unsigned short* kb0 = smem + li * 64 + ((g ^ swz) << 3);
  const unsigned short* kb1 = smem + li * 64 + (((4 + g) ^ swz) << 3);
  const unsigned short* vbE = smem + 8192 + li * 64 + (((2 * g) ^ swz) << 3);
  const unsigned short* vbO = smem + 8192 + li * 64 + (((2 * g + 1) ^ swz) << 3);

  float m_run[2] = {-1e30f, -1e30f}, l_lane[2] = {0.f, 0.f};
  f32x4 acc[2][4];
#pragma unroll
  for (int u = 0; u < 2; ++u)
#pragma unroll
    for (int t = 0; t < 4; ++t) acc[u][t] = f32x4{0.f, 0.f, 0.f, 0.f};

  // prologue: stage tile 0 into buf 0
  gl_lds16(ksrc, &smem[wave * 512]);
  gl_lds16(ksrc + 32 * 64, &smem[2048 + wave * 512]);
  gl_lds16(vsrc, &smem[8192 + wave * 512]);
  gl_lds16(vsrc + 32 * 2048, &smem[8192 + 2048 + wave * 512]);
  ksrc += 64 * 64;
  vsrc += 64;
  asm volatile("s_waitcnt vmcnt(0)" ::: "memory");
  __syncthreads();

  for (int t = 0; t < NT; t += 2) {
#pragma unroll
    for (int half = 0; half < 2; ++half) {
      const int CB = half * 4096;      // current buffer (compile-time per half)
      const int NB = (half ^ 1) * 4096;  // next buffer
      if (t + half + 1 < NT) {
        gl_lds16(ksrc, &smem[NB + wave * 512]);
        gl_lds16(ksrc + 32 * 64, &smem[NB + 2048 + wave * 512]);
        gl_lds16(vsrc, &smem[8192 + NB + wave * 512]);
        gl_lds16(vsrc + 32 * 2048, &smem[8192 + NB + 2048 + wave * 512]);
        ksrc += 64 * 64;
        vsrc += 64;
      }

      // K fragments (shared by both q-groups)
      bf16x8 kA[4][2];
#pragma unroll
      for (int tt = 0; tt < 4; ++tt) {
        kA[tt][0] = *(const bf16x8*)(kb0 + CB + tt * 1024);
        kA[tt][1] = *(const bf16x8*)(kb1 + CB + tt * 1024);
      }

      short4v p[2][4];
#pragma unroll
      for (int u = 0; u < 2; ++u) {
        f32x4 s[4];
#pragma unroll
        for (int tt = 0; tt < 4; ++tt) {
          f32x4 sv = {0.f, 0.f, 0.f, 0.f};
          sv = MFMA32(kA[tt][0], qf[u][0], sv, 0, 0, 0);
          sv = MFMA32(kA[tt][1], qf[u][1], sv, 0, 0, 0);
          s[tt] = sv;
        }
        float mx = fmaxf(fmaxf(s[0][0], s[0][1]), fmaxf(s[0][2], s[0][3]));
        mx = fmaxf(mx, fmaxf(fmaxf(s[1][0], s[1][1]), fmaxf(s[1][2], s[1][3])));
        mx = fmaxf(mx, fmaxf(fmaxf(s[2][0], s[2][1]), fmaxf(s[2][2], s[2][3])));
        mx = fmaxf(mx, fmaxf(fmaxf(s[3][0], s[3][1]), fmaxf(s[3][2], s[3][3])));
        if (!__all(mx <= m_run[u] + 8.f)) {  // rare: rescale with row-reduced max
          mx = fmaxf(mx, __shfl_xor(mx, 16));
          mx = fmaxf(mx, __shfl_xor(mx, 32));
          float mn = fmaxf(m_run[u], mx);
          float corr = __builtin_amdgcn_exp2f(m_run[u] - mn);
          l_lane[u] *= corr;
#pragma unroll
          for (int tt = 0; tt < 4; ++tt) acc[u][tt] *= corr;
          m_run[u] = mn;
        }
        float ts = 0.f;
#pragma unroll
        for (int tt = 0; tt < 4; ++tt) {
          float e0 = __builtin_amdgcn_exp2f(s[tt][0] - m_run[u]);
          float e1 = __builtin_amdgcn_exp2f(s[tt][1] - m_run[u]);
          float e2 = __builtin_amdgcn_exp2f(s[tt][2] - m_run[u]);
          float e3 = __builtin_amdgcn_exp2f(s[tt][3] - m_run[u]);
          ts += (e0 + e1) + (e2 + e3);
          p[u][tt] = pack_bf16x4(e0, e1, e2, e3);
        }
        l_lane[u] += ts;
      }

      // V fragments (permuted layout: lane's 4 k-slots contiguous) + PV
#pragma unroll
      for (int dd = 0; dd < 4; ++dd) {
        short8v ve = *(const short8v*)(vbE + CB + dd * 1024);
        short8v vo = *(const short8v*)(vbO + CB + dd * 1024);
        short4v v0 = __builtin_shufflevector(ve, ve, 0, 1, 2, 3);
        short4v v1 = __builtin_shufflevector(ve, ve, 4, 5, 6, 7);
        short4v v2 = __builtin_shufflevector(vo, vo, 0, 1, 2, 3);
        short4v v3 = __builtin_shufflevector(vo, vo, 4, 5, 6, 7);
#pragma unroll
        for (int u = 0; u < 2; ++u) {
          acc[u][dd] = MFMA16K(v0, p[u][0], acc[u][dd], 0, 0, 0);
          acc[u][dd] = MFMA16K(v1, p[u][1], acc[u][dd], 0, 0, 0);
          acc[u][dd] = MFMA16K(v2, p[u][2], acc[u][dd], 0, 0, 0);
          acc[u][dd] = MFMA16K(v3, p[u][3], acc[u][dd], 0, 0, 0);
        }
      }
      __syncthreads();
    }
  }

#pragma unroll
  for (int u = 0; u < 2; ++u) {
    float lv = l_lane[u];
    lv += __shfl_xor(lv, 16);
    lv += __shfl_xor(lv, 32);
    if constexpr (NS == 1) {
      float inv = 1.f / lv;
      unsigned short* orow =
          aout + ((size_t)(b * 2048 + bx * 128 + wave * 32 + u * 16 + li)) * KPAD + h * 64;
#pragma unroll
      for (int t = 0; t < 4; ++t) {
        ushort4 pk = make_ushort4(f2bf(acc[u][t][0] * inv), f2bf(acc[u][t][1] * inv),
                                  f2bf(acc[u][t][2] * inv), f2bf(acc[u][t][3] * inv));
        *(ushort4*)(orow + t * 16 + 4 * g) = pk;
      }
    } else {
      int tile = bh * 128 + bx * 8 + wave * 2 + u;
      float* pa = pacc + ((size_t)tile * NS + sp) * 1024 + li * 64;
#pragma unroll
      for (int t = 0; t < 4; ++t) *(f32x4*)(pa + t * 16 + 4 * g) = acc[u][t];
      if (g == 0) {
        float2 st = make_float2(m_run[u], lv);
        *(float2*)(pml + ((size_t)tile * NS + sp) * 32 + li * 2) = st;
      }
    }
  }
}

// combine split-KV partials -> aout bf16
__global__ __launch_bounds__(256) void k_combine(const float* __restrict__ pacc,
                                                 const float* __restrict__ pml,
                                                 unsigned short* __restrict__ aout, int NS) {
  int tile = blockIdx.x;  // bh*128 + qt
  int bh = tile >> 7, qt = tile & 127;
  int b = bh / 9, h = bh - b * 9;
  int d = threadIdx.x & 63, q0 = threadIdx.x >> 6;
  for (int q = q0; q < 16; q += 4) {
    const float* ml = pml + (size_t)tile * NS * 32 + q * 2;
    float M = -1e30f;
    for (int sp = 0; sp < NS; ++sp) M = fmaxf(M, ml[sp * 32]);
    float num = 0.f, den = 0.f;
    const float* pa = pacc + (size_t)tile * NS * 1024 + q * 64 + d;
    for (int sp = 0; sp < NS; ++sp) {
      float w = __builtin_amdgcn_exp2f(ml[sp * 32] - M);
      den += w * ml[sp * 32 + 1];
      num += w * pa[(size_t)sp * 1024];
    }
    aout[((size_t)(b * 2048 + qt * 16 + q)) * KPAD + h * 64 + d] = f2bf(num / den);
  }
}

// ---------------- launch ----------------

extern "C" void kernel_launch(void* const* d_in, const int* in_sizes, int n_in,
                              void* d_out, int out_size, void* d_ws, size_t ws_size,
                              hipStream_t stream) {
  const float* x  = (const float*)d_in[0];
  const float* y  = (const float*)d_in[1];
  const float* cx = (const float*)d_in[2];
  const float* cy = (const float*)d_in[3];
  const float* Wq = (const float*)d_in[4];
  const float* Wk = (const float*)d_in[5];
  const float* Wv = (const float*)d_in[6];
  const float* Wo = (const float*)d_in[7];
  const float* cs = (const float*)d_in[8];

  char* w = (char*)d_ws;
  auto take = [&](size_t bytes) {
    char* p = w;
    w += (bytes + 255) & ~(size_t)255;
    return p;
  };
  unsigned short* posed_x = (unsigned short*)take((size_t)4096 * KPAD * 2);
  unsigned short* posed_y = (unsigned short*)take((size_t)4096 * KPAD * 2);
  unsigned short* wqT = (unsigned short*)take((size_t)512 * KPAD * 2);
  unsigned short* wkT = (unsigned short*)take((size_t)512 * KPAD * 2);
  unsigned short* wvT = (unsigned short*)take((size_t)576 * KPAD * 2);
  unsigned short* woT = (unsigned short*)take((size_t)512 * KPAD * 2);
  unsigned short* qbuf = (unsigned short*)take((size_t)2 * 9 * 2048 * 64 * 2);
  unsigned short* kbuf = (unsigned short*)take((size_t)2 * 9 * 2048 * 64 * 2);
  unsigned short* vtb  = (unsigned short*)take((size_t)2 * 9 * 64 * 2048 * 2);
  unsigned short* aout = (unsigned short*)take((size_t)4096 * KPAD * 2);

  size_t base_used = (size_t)(w - (char*)d_ws);
  auto fits = [&](int ns) {
    return base_used + (size_t)2304 * ns * (1024 + 32) * 4 + 1024 <= ws_size;
  };
  int NS = fits(4) ? 4 : (fits(2) ? 2 : 1);
  float* pacc = nullptr;
  float* pml = nullptr;
  if (NS > 1) {
    pacc = (float*)take((size_t)2304 * NS * 1024 * 4);
    pml  = (float*)take((size_t)2304 * NS * 32 * 4);
  }

  k_pack_posed<<<(4096 * (KPAD / 4) + 255) / 256, 256, 0, stream>>>(x, cx, posed_x, 4096);
  k_pack_posed<<<(4096 * (KPAD / 4) + 255) / 256, 256, 0, stream>>>(y, cy, posed_y, 4096);
  dim3 gw(KPAD / 32, 512 / 32);
  dim3 gw9(KPAD / 32, 576 / 32);
  k_pack_wT<<<gw, 256, 0, stream>>>(Wq, wqT, 515, 512);
  k_pack_wT<<<gw, 256, 0, stream>>>(Wk, wkT, 515, 512);
  k_pack_wT<<<gw9, 256, 0, stream>>>(Wv, wvT, 515, 576);
  k_pack_wT<<<dim3(KPAD / 32, 512 / 32), 256, 0, stream>>>(Wo, woT, 576, 512);
  k_pack_ch<<<(4096 * 16 + 255) / 256, 256, 0, stream>>>(cx, qbuf, cs);
  k_pack_ch<<<(4096 * 16 + 255) / 256, 256, 0, stream>>>(cy, kbuf, nullptr);

  const float qsc = 0.125f * LOG2E;
  dim3 gq(64, 8);
  k_gemm<0><<<gq, 512, 0, stream>>>(posed_x, wqT, qbuf, 512, qsc);
  k_gemm<0><<<gq, 512, 0, stream>>>(posed_y, wkT, kbuf, 512, 1.f);
  dim3 gv(64, 9);
  k_gemm<1><<<gv, 512, 0, stream>>>(posed_y, wvT, vtb, 576, 1.f);

  dim3 ga(16, 9, 2 * NS);
  if (NS == 4)      k_attn<4><<<ga, 256, 0, stream>>>(qbuf, kbuf, vtb, aout, pacc, pml);
  else if (NS == 2) k_attn<2><<<ga, 256, 0, stream>>>(qbuf, kbuf, vtb, aout, pacc, pml);
  else              k_attn<1><<<ga, 256, 0, stream>>>(qbuf, kbuf, vtb, aout, pacc, pml);
  if (NS > 1) k_combine<<<2304, 256, 0, stream>>>(pacc, pml, aout, NS);

  dim3 go(64, 8);
  k_gemm<2><<<go, 512, 0, stream>>>(aout, woT, d_out, 512, 1.f);
}

// Round 6
// 111.100 us; speedup vs baseline: 3.3659x; 1.0297x over previous
//
#include <hip/hip_runtime.h>

typedef __bf16 bf16x8 __attribute__((ext_vector_type(8)));
typedef short short4v __attribute__((ext_vector_type(4)));
typedef short short8v __attribute__((ext_vector_type(8)));
typedef float f32x4 __attribute__((ext_vector_type(4)));

#define MFMA32 __builtin_amdgcn_mfma_f32_16x16x32_bf16
#define MFMA16K __builtin_amdgcn_mfma_f32_16x16x16bf16_1k

#define KPAD 576
#define LOG2E 1.44269504f

__device__ __forceinline__ unsigned short f2bf(float f) {
  unsigned u = __float_as_uint(f);
  u += 0x7FFFu + ((u >> 16) & 1u);
  return (unsigned short)(u >> 16);
}

__device__ __forceinline__ unsigned cvtpk_bf16(float a, float b) {
  unsigned r;
  asm("v_cvt_pk_bf16_f32 %0, %1, %2" : "=v"(r) : "v"(a), "v"(b));
  return r;  // lo = bf16(a), hi = bf16(b)
}

__device__ __forceinline__ short4v pack_bf16x4(float e0, float e1, float e2, float e3) {
  union { unsigned u[2]; short4v s; } pu;
  pu.u[0] = cvtpk_bf16(e0, e1);
  pu.u[1] = cvtpk_bf16(e2, e3);
  return pu.s;
}

__device__ __forceinline__ void gl_lds16(const void* g, void* l) {
  __builtin_amdgcn_global_load_lds((const __attribute__((address_space(1))) unsigned int*)g,
                                   (__attribute__((address_space(3))) unsigned int*)l, 16, 0, 0);
}

#define FENCE() asm volatile("" ::: "memory")
#define WAIT_LGKM0() do { asm volatile("s_waitcnt lgkmcnt(0)" ::: "memory"); \
                          __builtin_amdgcn_sched_barrier(0); } while (0)

// ---------------- pack kernels ----------------

__global__ void k_pack_posed(const float* __restrict__ feat, const float* __restrict__ coord,
                             unsigned short* __restrict__ dst, int rows) {
  int i = blockIdx.x * 256 + threadIdx.x;  // groups of 4 cols
  if (i >= rows * (KPAD / 4)) return;
  int r = i / (KPAD / 4), c = (i - r * (KPAD / 4)) * 4;
  float4 v = {0.f, 0.f, 0.f, 0.f};
  if (c < 512) v = *(const float4*)(feat + (size_t)r * 512 + c);
  else if (c == 512) {
    v.x = coord[(size_t)r * 3];
    v.y = coord[(size_t)r * 3 + 1];
    v.z = coord[(size_t)r * 3 + 2];
  }
  ushort4 o = make_ushort4(f2bf(v.x), f2bf(v.y), f2bf(v.z), f2bf(v.w));
  *(ushort4*)(dst + (size_t)i * 4) = o;
}

__global__ void k_pack_wT(const float* __restrict__ w, unsigned short* __restrict__ dst,
                          int kin, int nout) {
  __shared__ unsigned short tile[32][33];
  int kc0 = blockIdx.x * 32, n0 = blockIdx.y * 32;
  int tx = threadIdx.x & 31, ty = threadIdx.x >> 5;  // 32 x 8
#pragma unroll
  for (int it = 0; it < 4; ++it) {
    int kc = kc0 + ty + it * 8;
    float v = (kc < kin) ? w[(size_t)kc * nout + n0 + tx] : 0.f;
    tile[ty + it * 8][tx] = f2bf(v);
  }
  __syncthreads();
#pragma unroll
  for (int it = 0; it < 4; ++it) {
    int n = n0 + ty + it * 8;
    dst[(size_t)n * KPAD + kc0 + tx] = tile[tx][ty + it * 8];
  }
}

__global__ void k_pack_ch(const float* __restrict__ coord, unsigned short* __restrict__ buf,
                          const float* __restrict__ cs) {
  int i = blockIdx.x * 256 + threadIdx.x;  // 4096 rows * 16 groups of 4
  if (i >= 4096 * 16) return;
  int row = i >> 4, d4 = (i & 15) * 4;
  int b = row >> 11, n = row & 2047;
  ushort4 o = make_ushort4(0, 0, 0, 0);
  if (d4 == 0) {
    float sc = cs ? cs[0] * LOG2E : 1.f;
    o.x = f2bf(coord[(size_t)row * 3] * sc);
    o.y = f2bf(coord[(size_t)row * 3 + 1] * sc);
    o.z = f2bf(coord[(size_t)row * 3 + 2] * sc);
  }
  *(ushort4*)(buf + (((size_t)b * 9 + 8) * 2048 + n) * 64 + d4) = o;
}

// ---------------- GEMM: C[m,n] = sum_k A[m,k]*BT[n,k], K=KPAD ----------------
// 64x64 tile, 8 waves, A+B LDS-staged, BK=64, double-buffered with counted
// vmcnt + raw barriers (no drain in loop), 2-step-ahead prefetch, full unroll.
template <int MODE>
__global__ __launch_bounds__(512) void k_gemm(const unsigned short* __restrict__ A,
                                              const unsigned short* __restrict__ BT,
                                              void* __restrict__ dstv, int Nout, float oscale) {
  __shared__ unsigned short smem[16384];  // [buf 0/8192][A 4096 | B 4096] ushorts
  const int m0 = blockIdx.x * 64;
  const int n0 = blockIdx.y * 64;
  const int tid = threadIdx.x;
  const int wave = tid >> 6, lane = tid & 63;
  const int li = lane & 15, g = lane >> 4;
  const int wm = (wave & 3) * 16;
  const int wn = (wave >> 2) * 32;
  const int swz = li & 7;

  const int srow = tid >> 3, sc = (tid & 7) ^ (srow & 7);
  const unsigned short* asrc = A + (size_t)(m0 + srow) * KPAD + sc * 8;
  const unsigned short* bsrc = BT + (size_t)(n0 + srow) * KPAD + sc * 8;

  auto stg = [&](int bufOff) {
    gl_lds16(asrc, (void*)(smem + bufOff + wave * 512));
    gl_lds16(bsrc, (void*)(smem + bufOff + 4096 + wave * 512));
    asrc += 64;
    bsrc += 64;
  };

  f32x4 acc[2];
#pragma unroll
  for (int j = 0; j < 2; ++j) acc[j] = f32x4{0.f, 0.f, 0.f, 0.f};

  stg(0);
  FENCE();
  stg(8192);
  asm volatile("s_waitcnt vmcnt(2)" ::: "memory");
  __builtin_amdgcn_s_barrier();

  constexpr int NSTEP = KPAD / 64;  // 9
#pragma unroll
  for (int s = 0; s < NSTEP; ++s) {
    const int CB = (s & 1) * 8192;
    const unsigned short* sa = smem + CB;
    const unsigned short* sb = smem + CB + 4096;
    bf16x8 af0 = *(const bf16x8*)(sa + (wm + li) * 64 + ((g ^ swz) << 3));
    bf16x8 af1 = *(const bf16x8*)(sa + (wm + li) * 64 + (((4 + g) ^ swz) << 3));
    bf16x8 b00 = *(const bf16x8*)(sb + (wn + li) * 64 + ((g ^ swz) << 3));
    bf16x8 b01 = *(const bf16x8*)(sb + (wn + li) * 64 + (((4 + g) ^ swz) << 3));
    bf16x8 b10 = *(const bf16x8*)(sb + (wn + 16 + li) * 64 + ((g ^ swz) << 3));
    bf16x8 b11 = *(const bf16x8*)(sb + (wn + 16 + li) * 64 + (((4 + g) ^ swz) << 3));
    WAIT_LGKM0();
    __builtin_amdgcn_s_barrier();
    if (s + 2 < NSTEP) stg(CB);
    __builtin_amdgcn_s_setprio(1);
    acc[0] = MFMA32(af0, b00, acc[0], 0, 0, 0);
    acc[0] = MFMA32(af1, b01, acc[0], 0, 0, 0);
    acc[1] = MFMA32(af0, b10, acc[1], 0, 0, 0);
    acc[1] = MFMA32(af1, b11, acc[1], 0, 0, 0);
    __builtin_amdgcn_s_setprio(0);
    if (s + 2 < NSTEP) {
      asm volatile("s_waitcnt vmcnt(2)" ::: "memory");
    } else if (s + 1 < NSTEP) {
      asm volatile("s_waitcnt vmcnt(0)" ::: "memory");
    }
    if (s + 1 < NSTEP) __builtin_amdgcn_s_barrier();
  }

  const int mr = m0 + wm + 4 * g;
  if constexpr (MODE == 2) {
    float* out = (float*)dstv;
#pragma unroll
    for (int j = 0; j < 2; ++j) {
      int col = n0 + wn + j * 16 + li;
#pragma unroll
      for (int r = 0; r < 4; ++r) out[(size_t)(mr + r) * Nout + col] = acc[j][r];
    }
  } else if constexpr (MODE == 0) {
    unsigned short* out = (unsigned short*)dstv;
#pragma unroll
    for (int j = 0; j < 2; ++j) {
      int col = n0 + wn + j * 16 + li;
      int h = col >> 6, d = col & 63;
#pragma unroll
      for (int r = 0; r < 4; ++r) {
        int m = mr + r;
        int b = m >> 11, seq = m & 2047;
        out[(((size_t)b * 9 + h) * 2048 + seq) * 64 + d] = f2bf(acc[j][r] * oscale);
      }
    }
  } else {
    unsigned short* out = (unsigned short*)dstv;
    int b = mr >> 11, seq0 = mr & 2047;  // r=0..3 consecutive kv
    int c0 = seq0 & 63;
    int npos = (seq0 & ~63) + ((c0 >> 2) & 3) * 16 + (c0 >> 4) * 4;  // permuted
#pragma unroll
    for (int j = 0; j < 2; ++j) {
      int col = n0 + wn + j * 16 + li;
      int h = col >> 6, d = col & 63;
      ushort4 pk = make_ushort4(f2bf(acc[j][0]), f2bf(acc[j][1]), f2bf(acc[j][2]), f2bf(acc[j][3]));
      *(ushort4*)(out + (((size_t)b * 9 + h) * 64 + d) * 2048 + npos) = pk;
    }
  }
}

// ---------------- flash attention, LDS-staged K/V, split-KV ----------------
// Block = 128 q-rows (4 waves x 2 groups of 16), KV stripe 2048/NS, 64-kv tiles.
// Counted-vmcnt pipeline: stage tile t+2 while computing t; 3 raw barriers per
// tile, no vmcnt(0) drain in the loop (T3/T4). setprio around MFMA (T5).
template <int NS>
__global__ __launch_bounds__(256) void k_attn(const unsigned short* __restrict__ qb,
                                              const unsigned short* __restrict__ kb,
                                              const unsigned short* __restrict__ vt,
                                              unsigned short* __restrict__ aout,
                                              float* __restrict__ pacc,
                                              float* __restrict__ pml) {
  constexpr int CH = 2048 / NS;
  constexpr int NT = CH / 64;
  constexpr int NBLK = 16 * 9 * 2 * NS;
  __shared__ unsigned short smem[16384];  // [0,8192): K dbuf ; [8192,16384): V dbuf

  int lin = blockIdx.x + 16 * (blockIdx.y + 9 * blockIdx.z);
  int nl = (lin & 7) * (NBLK / 8) + (lin >> 3);
  int bx = nl & 15;
  int rest = nl >> 4;
  int h = rest % 9;
  int z = rest / 9;
  int b = z / NS, sp = z - b * NS;

  const int wave = threadIdx.x >> 6, lane = threadIdx.x & 63;
  const int li = lane & 15, g = lane >> 4;
  const int bh = b * 9 + h;
  const int kvbase = sp * CH;
  const int swz = li & 7;

  // Q fragments (scale pre-folded): 2 groups of 16 rows
  bf16x8 qf[2][2];
#pragma unroll
  for (int u = 0; u < 2; ++u) {
    const unsigned short* qp =
        qb + ((size_t)bh * 2048 + bx * 128 + wave * 32 + u * 16 + li) * 64 + g * 8;
    qf[u][0] = *(const bf16x8*)qp;
    qf[u][1] = *(const bf16x8*)(qp + 32);
  }

  // staging source pointers (row = tid>>3 in 0..31, +32 via offset)
  const int srow = threadIdx.x >> 3;
  const int ssc = (threadIdx.x & 7) ^ (srow & 7);
  const unsigned short* ksrc = kb + ((size_t)bh * 2048 + kvbase + srow) * 64 + ssc * 8;
  const unsigned short* vsrc = vt + ((size_t)bh * 64 + srow) * 2048 + kvbase + ssc * 8;

  auto stageK = [&](int bufOff) {
    gl_lds16(ksrc, (void*)(smem + bufOff + wave * 512));
    gl_lds16(ksrc + 32 * 64, (void*)(smem + bufOff + 2048 + wave * 512));
    ksrc += 64 * 64;
  };
  auto stageV = [&](int bufOff) {
    gl_lds16(vsrc, (void*)(smem + 8192 + bufOff + wave * 512));
    gl_lds16(vsrc + 32 * 2048, (void*)(smem + 8192 + bufOff + 2048 + wave * 512));
    vsrc += 64;
  };

  // per-lane LDS frag base pointers (ushort units)
  const unsigned short* kb0 = smem + li * 64 + ((g ^ swz) << 3);
  const unsigned short* kb1 = smem + li * 64 + (((4 + g) ^ swz) << 3);
  const unsigned short* vbE = smem + 8192 + li * 64 + (((2 * g) ^ swz) << 3);
  const unsigned short* vbO = smem + 8192 + li * 64 + (((2 * g + 1) ^ swz) << 3);

  float m_run[2] = {-1e30f, -1e30f}, l_lane[2] = {0.f, 0.f};
  f32x4 acc[2][4];
#pragma unroll
  for (int u = 0; u < 2; ++u)
#pragma unroll
    for (int t = 0; t < 4; ++t) acc[u][t] = f32x4{0.f, 0.f, 0.f, 0.f};

  // prologue: 2 tiles in flight; vmcnt queue = K0,V0,K1,V1 (fences pin order)
  stageK(0);
  stageV(0);
  FENCE();
  stageK(4096);
  stageV(4096);
  asm volatile("s_waitcnt vmcnt(4)" ::: "memory");
  __builtin_amdgcn_s_barrier();

#pragma unroll
  for (int t = 0; t < NT; ++t) {
    const int CB = (t & 1) * 4096;

    // ---- QK phase (reads interleaved, 2 K-frags live) ----
    f32x4 s[2][4];
    __builtin_amdgcn_s_setprio(1);
#pragma unroll
    for (int tt = 0; tt < 4; ++tt) {
      bf16x8 k0 = *(const bf16x8*)(kb0 + CB + tt * 1024);
      bf16x8 k1 = *(const bf16x8*)(kb1 + CB + tt * 1024);
      f32x4 sv0 = {0.f, 0.f, 0.f, 0.f}, sv1 = {0.f, 0.f, 0.f, 0.f};
      sv0 = MFMA32(k0, qf[0][0], sv0, 0, 0, 0);
      sv0 = MFMA32(k1, qf[0][1], sv0, 0, 0, 0);
      sv1 = MFMA32(k0, qf[1][0], sv1, 0, 0, 0);
      sv1 = MFMA32(k1, qf[1][1], sv1, 0, 0, 0);
      s[0][tt] = sv0;
      s[1][tt] = sv1;
    }
    __builtin_amdgcn_s_setprio(0);
    WAIT_LGKM0();
    __builtin_amdgcn_s_barrier();  // all waves done reading K[CB]
    if (t + 2 < NT) stageK(CB);

    // ---- softmax (defer-max, per-lane l, log2 domain) ----
    short4v p[2][4];
#pragma unroll
    for (int u = 0; u < 2; ++u) {
      float mx = fmaxf(fmaxf(s[u][0][0], s[u][0][1]), fmaxf(s[u][0][2], s[u][0][3]));
      mx = fmaxf(mx, fmaxf(fmaxf(s[u][1][0], s[u][1][1]), fmaxf(s[u][1][2], s[u][1][3])));
      mx = fmaxf(mx, fmaxf(fmaxf(s[u][2][0], s[u][2][1]), fmaxf(s[u][2][2], s[u][2][3])));
      mx = fmaxf(mx, fmaxf(fmaxf(s[u][3][0], s[u][3][1]), fmaxf(s[u][3][2], s[u][3][3])));
      if (!__all(mx <= m_run[u] + 8.f)) {  // rare: rescale with row-reduced max
        mx = fmaxf(mx, __shfl_xor(mx, 16));
        mx = fmaxf(mx, __shfl_xor(mx, 32));
        float mn = fmaxf(m_run[u], mx);
        float corr = __builtin_amdgcn_exp2f(m_run[u] - mn);
        l_lane[u] *= corr;
#pragma unroll
        for (int tt = 0; tt < 4; ++tt) acc[u][tt] *= corr;
        m_run[u] = mn;
      }
      float ts = 0.f;
#pragma unroll
      for (int tt = 0; tt < 4; ++tt) {
        float e0 = __builtin_amdgcn_exp2f(s[u][tt][0] - m_run[u]);
        float e1 = __builtin_amdgcn_exp2f(s[u][tt][1] - m_run[u]);
        float e2 = __builtin_amdgcn_exp2f(s[u][tt][2] - m_run[u]);
        float e3 = __builtin_amdgcn_exp2f(s[u][tt][3] - m_run[u]);
        ts += (e0 + e1) + (e2 + e3);
        p[u][tt] = pack_bf16x4(e0, e1, e2, e3);
      }
      l_lane[u] += ts;
    }

    // ---- PV phase (reads interleaved; permuted V layout) ----
    __builtin_amdgcn_s_setprio(1);
#pragma unroll
    for (int dd = 0; dd < 4; ++dd) {
      short8v ve = *(const short8v*)(vbE + CB + dd * 1024);
      short8v vo = *(const short8v*)(vbO + CB + dd * 1024);
      short4v v0 = __builtin_shufflevector(ve, ve, 0, 1, 2, 3);
      short4v v1 = __builtin_shufflevector(ve, ve, 4, 5, 6, 7);
      short4v v2 = __builtin_shufflevector(vo, vo, 0, 1, 2, 3);
      short4v v3 = __builtin_shufflevector(vo, vo, 4, 5, 6, 7);
#pragma unroll
      for (int u = 0; u < 2; ++u) {
        acc[u][dd] = MFMA16K(v0, p[u][0], acc[u][dd], 0, 0, 0);
        acc[u][dd] = MFMA16K(v1, p[u][1], acc[u][dd], 0, 0, 0);
        acc[u][dd] = MFMA16K(v2, p[u][2], acc[u][dd], 0, 0, 0);
        acc[u][dd] = MFMA16K(v3, p[u][3], acc[u][dd], 0, 0, 0);
      }
    }
    __builtin_amdgcn_s_setprio(0);
    WAIT_LGKM0();
    __builtin_amdgcn_s_barrier();  // all waves done reading V[CB]
    if (t + 2 < NT) stageV(CB);

    // wait for tile t+1's staging (issued one tile ago), then release
    if (t + 2 < NT) {
      asm volatile("s_waitcnt vmcnt(4)" ::: "memory");
    } else if (t + 1 < NT) {
      asm volatile("s_waitcnt vmcnt(0)" ::: "memory");
    }
    if (t + 1 < NT) __builtin_amdgcn_s_barrier();
  }

#pragma unroll
  for (int u = 0; u < 2; ++u) {
    float lv = l_lane[u];
    lv += __shfl_xor(lv, 16);
    lv += __shfl_xor(lv, 32);
    if constexpr (NS == 1) {
      float inv = 1.f / lv;
      unsigned short* orow =
          aout + ((size_t)(b * 2048 + bx * 128 + wave * 32 + u * 16 + li)) * KPAD + h * 64;
#pragma unroll
      for (int t = 0; t < 4; ++t) {
        ushort4 pk = make_ushort4(f2bf(acc[u][t][0] * inv), f2bf(acc[u][t][1] * inv),
                                  f2bf(acc[u][t][2] * inv), f2bf(acc[u][t][3] * inv));
        *(ushort4*)(orow + t * 16 + 4 * g) = pk;
      }
    } else {
      int tile = bh * 128 + bx * 8 + wave * 2 + u;
      float* pa = pacc + ((size_t)tile * NS + sp) * 1024 + li * 64;
#pragma unroll
      for (int t = 0; t < 4; ++t) *(f32x4*)(pa + t * 16 + 4 * g) = acc[u][t];
      if (g == 0) {
        float2 st = make_float2(m_run[u], lv);
        *(float2*)(pml + ((size_t)tile * NS + sp) * 32 + li * 2) = st;
      }
    }
  }
}

// combine split-KV partials -> aout bf16
__global__ __launch_bounds__(256) void k_combine(const float* __restrict__ pacc,
                                                 const float* __restrict__ pml,
                                                 unsigned short* __restrict__ aout, int NS) {
  int tile = blockIdx.x;  // bh*128 + qt
  int bh = tile >> 7, qt = tile & 127;
  int b = bh / 9, h = bh - b * 9;
  int d = threadIdx.x & 63, q0 = threadIdx.x >> 6;
  for (int q = q0; q < 16; q += 4) {
    const float* ml = pml + (size_t)tile * NS * 32 + q * 2;
    float M = -1e30f;
    for (int sp = 0; sp < NS; ++sp) M = fmaxf(M, ml[sp * 32]);
    float num = 0.f, den = 0.f;
    const float* pa = pacc + (size_t)tile * NS * 1024 + q * 64 + d;
    for (int sp = 0; sp < NS; ++sp) {
      float w = __builtin_amdgcn_exp2f(ml[sp * 32] - M);
      den += w * ml[sp * 32 + 1];
      num += w * pa[(size_t)sp * 1024];
    }
    aout[((size_t)(b * 2048 + qt * 16 + q)) * KPAD + h * 64 + d] = f2bf(num / den);
  }
}

// ---------------- launch ----------------

extern "C" void kernel_launch(void* const* d_in, const int* in_sizes, int n_in,
                              void* d_out, int out_size, void* d_ws, size_t ws_size,
                              hipStream_t stream) {
  const float* x  = (const float*)d_in[0];
  const float* y  = (const float*)d_in[1];
  const float* cx = (const float*)d_in[2];
  const float* cy = (const float*)d_in[3];
  const float* Wq = (const float*)d_in[4];
  const float* Wk = (const float*)d_in[5];
  const float* Wv = (const float*)d_in[6];
  const float* Wo = (const float*)d_in[7];
  const float* cs = (const float*)d_in[8];

  char* w = (char*)d_ws;
  auto take = [&](size_t bytes) {
    char* p = w;
    w += (bytes + 255) & ~(size_t)255;
    return p;
  };
  unsigned short* posed_x = (unsigned short*)take((size_t)4096 * KPAD * 2);
  unsigned short* posed_y = (unsigned short*)take((size_t)4096 * KPAD * 2);
  unsigned short* wqT = (unsigned short*)take((size_t)512 * KPAD * 2);
  unsigned short* wkT = (unsigned short*)take((size_t)512 * KPAD * 2);
  unsigned short* wvT = (unsigned short*)take((size_t)576 * KPAD * 2);
  unsigned short* woT = (unsigned short*)take((size_t)512 * KPAD * 2);
  unsigned short* qbuf = (unsigned short*)take((size_t)2 * 9 * 2048 * 64 * 2);
  unsigned short* kbuf = (unsigned short*)take((size_t)2 * 9 * 2048 * 64 * 2);
  unsigned short* vtb  = (unsigned short*)take((size_t)2 * 9 * 64 * 2048 * 2);
  unsigned short* aout = (unsigned short*)take((size_t)4096 * KPAD * 2);

  size_t base_used = (size_t)(w - (char*)d_ws);
  auto fits = [&](int ns) {
    return base_used + (size_t)2304 * ns * (1024 + 32) * 4 + 1024 <= ws_size;
  };
  int NS = fits(4) ? 4 : (fits(2) ? 2 : 1);
  float* pacc = nullptr;
  float* pml = nullptr;
  if (NS > 1) {
    pacc = (float*)take((size_t)2304 * NS * 1024 * 4);
    pml  = (float*)take((size_t)2304 * NS * 32 * 4);
  }

  k_pack_posed<<<(4096 * (KPAD / 4) + 255) / 256, 256, 0, stream>>>(x, cx, posed_x, 4096);
  k_pack_posed<<<(4096 * (KPAD / 4) + 255) / 256, 256, 0, stream>>>(y, cy, posed_y, 4096);
  dim3 gw(KPAD / 32, 512 / 32);
  dim3 gw9(KPAD / 32, 576 / 32);
  k_pack_wT<<<gw, 256, 0, stream>>>(Wq, wqT, 515, 512);
  k_pack_wT<<<gw, 256, 0, stream>>>(Wk, wkT, 515, 512);
  k_pack_wT<<<gw9, 256, 0, stream>>>(Wv, wvT, 515, 576);
  k_pack_wT<<<dim3(KPAD / 32, 512 / 32), 256, 0, stream>>>(Wo, woT, 576, 512);
  k_pack_ch<<<(4096 * 16 + 255) / 256, 256, 0, stream>>>(cx, qbuf, cs);
  k_pack_ch<<<(4096 * 16 + 255) / 256, 256, 0, stream>>>(cy, kbuf, nullptr);

  const float qsc = 0.125f * LOG2E;
  dim3 gq(64, 8);
  k_gemm<0><<<gq, 512, 0, stream>>>(posed_x, wqT, qbuf, 512, qsc);
  k_gemm<0><<<gq, 512, 0, stream>>>(posed_y, wkT, kbuf, 512, 1.f);
  dim3 gv(64, 9);
  k_gemm<1><<<gv, 512, 0, stream>>>(posed_y, wvT, vtb, 576, 1.f);

  dim3 ga(16, 9, 2 * NS);
  if (NS == 4)      k_attn<4><<<ga, 256, 0, stream>>>(qbuf, kbuf, vtb, aout, pacc, pml);
  else if (NS == 2) k_attn<2><<<ga, 256, 0, stream>>>(qbuf, kbuf, vtb, aout, pacc, pml);
  else              k_attn<1><<<ga, 256, 0, stream>>>(qbuf, kbuf, vtb, aout, pacc, pml);
  if (NS > 1) k_combine<<<2304, 256, 0, stream>>>(pacc, pml, aout, NS);

  dim3 go(64, 8);
  k_gemm<2><<<go, 512, 0, stream>>>(aout, woT, d_out, 512, 1.f);
}

// Round 7
// 100.706 us; speedup vs baseline: 3.7133x; 1.1032x over previous
//
#include <hip/hip_runtime.h>

typedef __bf16 bf16x8 __attribute__((ext_vector_type(8)));
typedef short short4v __attribute__((ext_vector_type(4)));
typedef short short8v __attribute__((ext_vector_type(8)));
typedef float f32x4 __attribute__((ext_vector_type(4)));

#define MFMA32 __builtin_amdgcn_mfma_f32_16x16x32_bf16
#define MFMA16K __builtin_amdgcn_mfma_f32_16x16x16bf16_1k

#define KPAD 576
#define LOG2E 1.44269504f

__device__ __forceinline__ unsigned short f2bf(float f) {
  unsigned u = __float_as_uint(f);
  u += 0x7FFFu + ((u >> 16) & 1u);
  return (unsigned short)(u >> 16);
}

__device__ __forceinline__ unsigned cvtpk_bf16(float a, float b) {
  unsigned r;
  asm("v_cvt_pk_bf16_f32 %0, %1, %2" : "=v"(r) : "v"(a), "v"(b));
  return r;  // lo = bf16(a), hi = bf16(b)
}

__device__ __forceinline__ short4v pack_bf16x4(float e0, float e1, float e2, float e3) {
  union { unsigned u[2]; short4v s; } pu;
  pu.u[0] = cvtpk_bf16(e0, e1);
  pu.u[1] = cvtpk_bf16(e2, e3);
  return pu.s;
}

__device__ __forceinline__ void gl_lds16(const void* g, void* l) {
  __builtin_amdgcn_global_load_lds((const __attribute__((address_space(1))) unsigned int*)g,
                                   (__attribute__((address_space(3))) unsigned int*)l, 16, 0, 0);
}

#define FENCE() asm volatile("" ::: "memory")
#define WAIT_LGKM0() do { asm volatile("s_waitcnt lgkmcnt(0)" ::: "memory"); \
                          __builtin_amdgcn_sched_barrier(0); } while (0)

// ---------------- pack kernels (fused) ----------------

// rows 0..4095 from (fa,ca), rows 4096..8191 from (fb,cb) -> bf16 [8192, 576]
__global__ void k_pack_posed2(const float* __restrict__ fa, const float* __restrict__ ca,
                              const float* __restrict__ fb, const float* __restrict__ cb,
                              unsigned short* __restrict__ dst) {
  int i = blockIdx.x * 256 + threadIdx.x;  // groups of 4 cols
  if (i >= 8192 * (KPAD / 4)) return;
  int r = i / (KPAD / 4), c = (i - r * (KPAD / 4)) * 4;
  const float* feat = (r < 4096) ? fa : fb;
  const float* coord = (r < 4096) ? ca : cb;
  int rr = r & 4095;
  float4 v = {0.f, 0.f, 0.f, 0.f};
  if (c < 512) v = *(const float4*)(feat + (size_t)rr * 512 + c);
  else if (c == 512) {
    v.x = coord[(size_t)rr * 3];
    v.y = coord[(size_t)rr * 3 + 1];
    v.z = coord[(size_t)rr * 3 + 2];
  }
  ushort4 o = make_ushort4(f2bf(v.x), f2bf(v.y), f2bf(v.z), f2bf(v.w));
  *(ushort4*)(dst + (size_t)i * 4) = o;
}

// all four weights: dst[n,kc] = (kc<kin) ? w[kc,n] : 0; z selects matrix
__global__ void k_pack_w_all(const float* __restrict__ Wq, const float* __restrict__ Wk,
                             const float* __restrict__ Wv, const float* __restrict__ Wo,
                             unsigned short* __restrict__ wqT, unsigned short* __restrict__ wkT,
                             unsigned short* __restrict__ wvT, unsigned short* __restrict__ woT) {
  __shared__ unsigned short tile[32][33];
  int z = blockIdx.z;
  int nout = (z == 2) ? 576 : 512;
  if (blockIdx.y * 32 >= nout) return;
  int kin = (z == 3) ? 576 : 515;
  const float* w = (z == 0) ? Wq : (z == 1) ? Wk : (z == 2) ? Wv : Wo;
  unsigned short* dst = (z == 0) ? wqT : (z == 1) ? wkT : (z == 2) ? wvT : woT;
  int kc0 = blockIdx.x * 32, n0 = blockIdx.y * 32;
  int tx = threadIdx.x & 31, ty = threadIdx.x >> 5;  // 32 x 8
#pragma unroll
  for (int it = 0; it < 4; ++it) {
    int kc = kc0 + ty + it * 8;
    float v = (kc < kin) ? w[(size_t)kc * nout + n0 + tx] : 0.f;
    tile[ty + it * 8][tx] = f2bf(v);
  }
  __syncthreads();
#pragma unroll
  for (int it = 0; it < 4; ++it) {
    int n = n0 + ty + it * 8;
    dst[(size_t)n * KPAD + kc0 + tx] = tile[tx][ty + it * 8];
  }
}

// coord head (h=8) of q and k buffers (q side scaled by cs*log2e)
__global__ void k_pack_ch2(const float* __restrict__ cx, const float* __restrict__ cy,
                           unsigned short* __restrict__ qbuf, unsigned short* __restrict__ kbuf,
                           const float* __restrict__ cs) {
  int i = blockIdx.x * 256 + threadIdx.x;  // 8192 rows * 16 groups of 4
  if (i >= 8192 * 16) return;
  int rr = i >> 4, d4 = (i & 15) * 4;
  int qside = rr < 4096;
  int row = rr & 4095;
  const float* coord = qside ? cx : cy;
  unsigned short* buf = qside ? qbuf : kbuf;
  int b = row >> 11, n = row & 2047;
  ushort4 o = make_ushort4(0, 0, 0, 0);
  if (d4 == 0) {
    float sc = qside ? cs[0] * LOG2E : 1.f;
    o.x = f2bf(coord[(size_t)row * 3] * sc);
    o.y = f2bf(coord[(size_t)row * 3 + 1] * sc);
    o.z = f2bf(coord[(size_t)row * 3 + 2] * sc);
  }
  *(ushort4*)(buf + (((size_t)b * 9 + 8) * 2048 + n) * 64 + d4) = o;
}

// ---------------- fused projection GEMM (Q/K/V via blockIdx.z) ----------------
// C[m,n] = sum_k A[m,k]*BT[n,k], K=KPAD. 64x64 tile, 8 waves, A+B LDS-staged,
// counted vmcnt + raw barriers, 2-step-ahead prefetch.
// z=0: posed_x*Wq -> qbuf (scaled); z=1: posed_y*Wk -> kbuf; z=2: posed_y*Wv -> vtb.
__global__ __launch_bounds__(512) void k_proj(const unsigned short* __restrict__ px,
                                              const unsigned short* __restrict__ py,
                                              const unsigned short* __restrict__ wq,
                                              const unsigned short* __restrict__ wk,
                                              const unsigned short* __restrict__ wv,
                                              unsigned short* __restrict__ qbuf,
                                              unsigned short* __restrict__ kbuf,
                                              unsigned short* __restrict__ vtb, float qsc) {
  __shared__ unsigned short smem[16384];
  const int z = blockIdx.z;
  if (z < 2 && blockIdx.y >= 8) return;
  const unsigned short* A = (z == 0) ? px : py;
  const unsigned short* BT = (z == 0) ? wq : (z == 1) ? wk : wv;

  const int m0 = blockIdx.x * 64;
  const int n0 = blockIdx.y * 64;
  const int tid = threadIdx.x;
  const int wave = tid >> 6, lane = tid & 63;
  const int li = lane & 15, g = lane >> 4;
  const int wm = (wave & 3) * 16;
  const int wn = (wave >> 2) * 32;
  const int swz = li & 7;

  const int srow = tid >> 3, sc = (tid & 7) ^ (srow & 7);
  const unsigned short* asrc = A + (size_t)(m0 + srow) * KPAD + sc * 8;
  const unsigned short* bsrc = BT + (size_t)(n0 + srow) * KPAD + sc * 8;

  auto stg = [&](int bufOff) {
    gl_lds16(asrc, (void*)(smem + bufOff + wave * 512));
    gl_lds16(bsrc, (void*)(smem + bufOff + 4096 + wave * 512));
    asrc += 64;
    bsrc += 64;
  };

  f32x4 acc[2];
#pragma unroll
  for (int j = 0; j < 2; ++j) acc[j] = f32x4{0.f, 0.f, 0.f, 0.f};

  stg(0);
  FENCE();
  stg(8192);
  asm volatile("s_waitcnt vmcnt(2)" ::: "memory");
  __builtin_amdgcn_s_barrier();

  constexpr int NSTEP = KPAD / 64;  // 9
#pragma unroll
  for (int s = 0; s < NSTEP; ++s) {
    const int CB = (s & 1) * 8192;
    const unsigned short* sa = smem + CB;
    const unsigned short* sb = smem + CB + 4096;
    bf16x8 af0 = *(const bf16x8*)(sa + (wm + li) * 64 + ((g ^ swz) << 3));
    bf16x8 af1 = *(const bf16x8*)(sa + (wm + li) * 64 + (((4 + g) ^ swz) << 3));
    bf16x8 b00 = *(const bf16x8*)(sb + (wn + li) * 64 + ((g ^ swz) << 3));
    bf16x8 b01 = *(const bf16x8*)(sb + (wn + li) * 64 + (((4 + g) ^ swz) << 3));
    bf16x8 b10 = *(const bf16x8*)(sb + (wn + 16 + li) * 64 + ((g ^ swz) << 3));
    bf16x8 b11 = *(const bf16x8*)(sb + (wn + 16 + li) * 64 + (((4 + g) ^ swz) << 3));
    WAIT_LGKM0();
    __builtin_amdgcn_s_barrier();
    if (s + 2 < NSTEP) stg(CB);
    __builtin_amdgcn_s_setprio(1);
    acc[0] = MFMA32(af0, b00, acc[0], 0, 0, 0);
    acc[0] = MFMA32(af1, b01, acc[0], 0, 0, 0);
    acc[1] = MFMA32(af0, b10, acc[1], 0, 0, 0);
    acc[1] = MFMA32(af1, b11, acc[1], 0, 0, 0);
    __builtin_amdgcn_s_setprio(0);
    if (s + 2 < NSTEP) {
      asm volatile("s_waitcnt vmcnt(2)" ::: "memory");
    } else if (s + 1 < NSTEP) {
      asm volatile("s_waitcnt vmcnt(0)" ::: "memory");
    }
    if (s + 1 < NSTEP) __builtin_amdgcn_s_barrier();
  }

  const int mr = m0 + wm + 4 * g;
  if (z == 2) {  // vT permuted layout
    int b = mr >> 11, seq0 = mr & 2047;
    int c0 = seq0 & 63;
    int npos = (seq0 & ~63) + ((c0 >> 2) & 3) * 16 + (c0 >> 4) * 4;
#pragma unroll
    for (int j = 0; j < 2; ++j) {
      int col = n0 + wn + j * 16 + li;
      int h = col >> 6, d = col & 63;
      ushort4 pk = make_ushort4(f2bf(acc[j][0]), f2bf(acc[j][1]), f2bf(acc[j][2]), f2bf(acc[j][3]));
      *(ushort4*)(vtb + (((size_t)b * 9 + h) * 64 + d) * 2048 + npos) = pk;
    }
  } else {
    unsigned short* out = z ? kbuf : qbuf;
    float oscale = z ? 1.f : qsc;
#pragma unroll
    for (int j = 0; j < 2; ++j) {
      int col = n0 + wn + j * 16 + li;
      int h = col >> 6, d = col & 63;
#pragma unroll
      for (int r = 0; r < 4; ++r) {
        int m = mr + r;
        int b = m >> 11, seq = m & 2047;
        out[(((size_t)b * 9 + h) * 2048 + seq) * 64 + d] = f2bf(acc[j][r] * oscale);
      }
    }
  }
}

// ---------------- output GEMM: d_out[m,n] = sum_k aout[m,k]*woT[n,k] ----------------
__global__ __launch_bounds__(512) void k_gemm_out(const unsigned short* __restrict__ A,
                                                  const unsigned short* __restrict__ BT,
                                                  float* __restrict__ out, int Nout) {
  __shared__ unsigned short smem[16384];
  const int m0 = blockIdx.x * 64;
  const int n0 = blockIdx.y * 64;
  const int tid = threadIdx.x;
  const int wave = tid >> 6, lane = tid & 63;
  const int li = lane & 15, g = lane >> 4;
  const int wm = (wave & 3) * 16;
  const int wn = (wave >> 2) * 32;
  const int swz = li & 7;

  const int srow = tid >> 3, sc = (tid & 7) ^ (srow & 7);
  const unsigned short* asrc = A + (size_t)(m0 + srow) * KPAD + sc * 8;
  const unsigned short* bsrc = BT + (size_t)(n0 + srow) * KPAD + sc * 8;

  auto stg = [&](int bufOff) {
    gl_lds16(asrc, (void*)(smem + bufOff + wave * 512));
    gl_lds16(bsrc, (void*)(smem + bufOff + 4096 + wave * 512));
    asrc += 64;
    bsrc += 64;
  };

  f32x4 acc[2];
#pragma unroll
  for (int j = 0; j < 2; ++j) acc[j] = f32x4{0.f, 0.f, 0.f, 0.f};

  stg(0);
  FENCE();
  stg(8192);
  asm volatile("s_waitcnt vmcnt(2)" ::: "memory");
  __builtin_amdgcn_s_barrier();

  constexpr int NSTEP = KPAD / 64;  // 9
#pragma unroll
  for (int s = 0; s < NSTEP; ++s) {
    const int CB = (s & 1) * 8192;
    const unsigned short* sa = smem + CB;
    const unsigned short* sb = smem + CB + 4096;
    bf16x8 af0 = *(const bf16x8*)(sa + (wm + li) * 64 + ((g ^ swz) << 3));
    bf16x8 af1 = *(const bf16x8*)(sa + (wm + li) * 64 + (((4 + g) ^ swz) << 3));
    bf16x8 b00 = *(const bf16x8*)(sb + (wn + li) * 64 + ((g ^ swz) << 3));
    bf16x8 b01 = *(const bf16x8*)(sb + (wn + li) * 64 + (((4 + g) ^ swz) << 3));
    bf16x8 b10 = *(const bf16x8*)(sb + (wn + 16 + li) * 64 + ((g ^ swz) << 3));
    bf16x8 b11 = *(const bf16x8*)(sb + (wn + 16 + li) * 64 + (((4 + g) ^ swz) << 3));
    WAIT_LGKM0();
    __builtin_amdgcn_s_barrier();
    if (s + 2 < NSTEP) stg(CB);
    __builtin_amdgcn_s_setprio(1);
    acc[0] = MFMA32(af0, b00, acc[0], 0, 0, 0);
    acc[0] = MFMA32(af1, b01, acc[0], 0, 0, 0);
    acc[1] = MFMA32(af0, b10, acc[1], 0, 0, 0);
    acc[1] = MFMA32(af1, b11, acc[1], 0, 0, 0);
    __builtin_amdgcn_s_setprio(0);
    if (s + 2 < NSTEP) {
      asm volatile("s_waitcnt vmcnt(2)" ::: "memory");
    } else if (s + 1 < NSTEP) {
      asm volatile("s_waitcnt vmcnt(0)" ::: "memory");
    }
    if (s + 1 < NSTEP) __builtin_amdgcn_s_barrier();
  }

  const int mr = m0 + wm + 4 * g;
#pragma unroll
  for (int j = 0; j < 2; ++j) {
    int col = n0 + wn + j * 16 + li;
#pragma unroll
    for (int r = 0; r < 4; ++r) out[(size_t)(mr + r) * Nout + col] = acc[j][r];
  }
}

// ---------------- flash attention: QBLK=256, LDS-staged K/V, split-KV ----------------
// Block = 256 q-rows (4 waves x 4 groups of 16), KV stripe 2048/NS, 64-kv tiles.
// Counted-vmcnt pipeline, 3 raw barriers/tile, no vmcnt(0) drain in loop.
template <int NS>
__global__ __launch_bounds__(256, 2) void k_attn(const unsigned short* __restrict__ qb,
                                                 const unsigned short* __restrict__ kb,
                                                 const unsigned short* __restrict__ vt,
                                                 unsigned short* __restrict__ aout,
                                                 float* __restrict__ pacc,
                                                 float* __restrict__ pml) {
  constexpr int CH = 2048 / NS;
  constexpr int NT = CH / 64;
  constexpr int NBLK = 8 * 9 * 2 * NS;
  __shared__ unsigned short smem[16384];  // [0,8192): K dbuf ; [8192,16384): V dbuf

  int lin = blockIdx.x + 8 * (blockIdx.y + 9 * blockIdx.z);
  int nl = (lin & 7) * (NBLK / 8) + (lin >> 3);
  int bx = nl & 7;
  int rest = nl >> 3;
  int h = rest % 9;
  int z = rest / 9;
  int b = z / NS, sp = z - b * NS;

  const int wave = threadIdx.x >> 6, lane = threadIdx.x & 63;
  const int li = lane & 15, g = lane >> 4;
  const int bh = b * 9 + h;
  const int kvbase = sp * CH;
  const int swz = li & 7;
  const int n0w = bx * 256 + wave * 64;  // wave's q base

  // Q fragments (scale pre-folded): 4 groups of 16 rows
  bf16x8 qf[4][2];
#pragma unroll
  for (int u = 0; u < 4; ++u) {
    const unsigned short* qp = qb + ((size_t)bh * 2048 + n0w + u * 16 + li) * 64 + g * 8;
    qf[u][0] = *(const bf16x8*)qp;
    qf[u][1] = *(const bf16x8*)(qp + 32);
  }

  // staging source pointers (row = tid>>3 in 0..31, +32 via offset)
  const int srow = threadIdx.x >> 3;
  const int ssc = (threadIdx.x & 7) ^ (srow & 7);
  const unsigned short* ksrc = kb + ((size_t)bh * 2048 + kvbase + srow) * 64 + ssc * 8;
  const unsigned short* vsrc = vt + ((size_t)bh * 64 + srow) * 2048 + kvbase + ssc * 8;

  auto stageK = [&](int bufOff) {
    gl_lds16(ksrc, (void*)(smem + bufOff + wave * 512));
    gl_lds16(ksrc + 32 * 64, (void*)(smem + bufOff + 2048 + wave * 512));
    ksrc += 64 * 64;
  };
  auto stageV = [&](int bufOff) {
    gl_lds16(vsrc, (void*)(smem + 8192 + bufOff + wave * 512));
    gl_lds16(vsrc + 32 * 2048, (void*)(smem + 8192 + bufOff + 2048 + wave * 512));
    vsrc += 64;
  };

  // per-lane LDS frag base pointers (ushort units)
  const unsigned short* kb0 = smem + li * 64 + ((g ^ swz) << 3);
  const unsigned short* kb1 = smem + li * 64 + (((4 + g) ^ swz) << 3);
  const unsigned short* vbE = smem + 8192 + li * 64 + (((2 * g) ^ swz) << 3);
  const unsigned short* vbO = smem + 8192 + li * 64 + (((2 * g + 1) ^ swz) << 3);

  float m_run[4] = {-1e30f, -1e30f, -1e30f, -1e30f};
  float l_lane[4] = {0.f, 0.f, 0.f, 0.f};
  f32x4 acc[4][4];
#pragma unroll
  for (int u = 0; u < 4; ++u)
#pragma unroll
    for (int t = 0; t < 4; ++t) acc[u][t] = f32x4{0.f, 0.f, 0.f, 0.f};

  // prologue: 2 tiles in flight; vmcnt queue = K0,V0,K1,V1
  stageK(0);
  stageV(0);
  FENCE();
  stageK(4096);
  stageV(4096);
  asm volatile("s_waitcnt vmcnt(4)" ::: "memory");
  __builtin_amdgcn_s_barrier();

#pragma unroll
  for (int t = 0; t < NT; ++t) {
    const int CB = (t & 1) * 4096;

    // ---- QK phase: s[u][tt] covers kv_local = 16tt + 4g + r ----
    f32x4 s[4][4];
    __builtin_amdgcn_s_setprio(1);
#pragma unroll
    for (int tt = 0; tt < 4; ++tt) {
      bf16x8 k0 = *(const bf16x8*)(kb0 + CB + tt * 1024);
      bf16x8 k1 = *(const bf16x8*)(kb1 + CB + tt * 1024);
#pragma unroll
      for (int u = 0; u < 4; ++u) {
        f32x4 sv = {0.f, 0.f, 0.f, 0.f};
        sv = MFMA32(k0, qf[u][0], sv, 0, 0, 0);
        sv = MFMA32(k1, qf[u][1], sv, 0, 0, 0);
        s[u][tt] = sv;
      }
    }
    __builtin_amdgcn_s_setprio(0);
    WAIT_LGKM0();
    __builtin_amdgcn_s_barrier();  // all waves done reading K[CB]
    if (t + 2 < NT) stageK(CB);

    // ---- softmax (defer-max, per-lane l) ----
    short4v p[4][4];
#pragma unroll
    for (int u = 0; u < 4; ++u) {
      float mx = fmaxf(fmaxf(s[u][0][0], s[u][0][1]), fmaxf(s[u][0][2], s[u][0][3]));
      mx = fmaxf(mx, fmaxf(fmaxf(s[u][1][0], s[u][1][1]), fmaxf(s[u][1][2], s[u][1][3])));
      mx = fmaxf(mx, fmaxf(fmaxf(s[u][2][0], s[u][2][1]), fmaxf(s[u][2][2], s[u][2][3])));
      mx = fmaxf(mx, fmaxf(fmaxf(s[u][3][0], s[u][3][1]), fmaxf(s[u][3][2], s[u][3][3])));
      if (!__all(mx <= m_run[u] + 8.f)) {
        mx = fmaxf(mx, __shfl_xor(mx, 16));
        mx = fmaxf(mx, __shfl_xor(mx, 32));
        float mn = fmaxf(m_run[u], mx);
        float corr = __builtin_amdgcn_exp2f(m_run[u] - mn);
        l_lane[u] *= corr;
#pragma unroll
        for (int tt = 0; tt < 4; ++tt) acc[u][tt] *= corr;
        m_run[u] = mn;
      }
      float ts = 0.f;
#pragma unroll
      for (int tt = 0; tt < 4; ++tt) {
        float e0 = __builtin_amdgcn_exp2f(s[u][tt][0] - m_run[u]);
        float e1 = __builtin_amdgcn_exp2f(s[u][tt][1] - m_run[u]);
        float e2 = __builtin_amdgcn_exp2f(s[u][tt][2] - m_run[u]);
        float e3 = __builtin_amdgcn_exp2f(s[u][tt][3] - m_run[u]);
        ts += (e0 + e1) + (e2 + e3);
        p[u][tt] = pack_bf16x4(e0, e1, e2, e3);
      }
      l_lane[u] += ts;
    }

    // ---- PV phase (permuted V layout) ----
    __builtin_amdgcn_s_setprio(1);
#pragma unroll
    for (int dd = 0; dd < 4; ++dd) {
      short8v ve = *(const short8v*)(vbE + CB + dd * 1024);
      short8v vo = *(const short8v*)(vbO + CB + dd * 1024);
      short4v v0 = __builtin_shufflevector(ve, ve, 0, 1, 2, 3);
      short4v v1 = __builtin_shufflevector(ve, ve, 4, 5, 6, 7);
      short4v v2 = __builtin_shufflevector(vo, vo, 0, 1, 2, 3);
      short4v v3 = __builtin_shufflevector(vo, vo, 4, 5, 6, 7);
#pragma unroll
      for (int u = 0; u < 4; ++u) {
        acc[u][dd] = MFMA16K(v0, p[u][0], acc[u][dd], 0, 0, 0);
        acc[u][dd] = MFMA16K(v1, p[u][1], acc[u][dd], 0, 0, 0);
        acc[u][dd] = MFMA16K(v2, p[u][2], acc[u][dd], 0, 0, 0);
        acc[u][dd] = MFMA16K(v3, p[u][3], acc[u][dd], 0, 0, 0);
      }
    }
    __builtin_amdgcn_s_setprio(0);
    WAIT_LGKM0();
    __builtin_amdgcn_s_barrier();  // all waves done reading V[CB]
    if (t + 2 < NT) stageV(CB);

    if (t + 2 < NT) {
      asm volatile("s_waitcnt vmcnt(4)" ::: "memory");
    } else if (t + 1 < NT) {
      asm volatile("s_waitcnt vmcnt(0)" ::: "memory");
    }
    if (t + 1 < NT) __builtin_amdgcn_s_barrier();
  }

#pragma unroll
  for (int u = 0; u < 4; ++u) {
    float lv = l_lane[u];
    lv += __shfl_xor(lv, 16);
    lv += __shfl_xor(lv, 32);
    if constexpr (NS == 1) {
      float inv = 1.f / lv;
      unsigned short* orow = aout + ((size_t)(b * 2048 + n0w + u * 16 + li)) * KPAD + h * 64;
#pragma unroll
      for (int t = 0; t < 4; ++t) {
        ushort4 pk = make_ushort4(f2bf(acc[u][t][0] * inv), f2bf(acc[u][t][1] * inv),
                                  f2bf(acc[u][t][2] * inv), f2bf(acc[u][t][3] * inv));
        *(ushort4*)(orow + t * 16 + 4 * g) = pk;
      }
    } else {
      int tile = bh * 128 + bx * 16 + wave * 4 + u;
      float* pa = pacc + ((size_t)tile * NS + sp) * 1024 + li * 64;
#pragma unroll
      for (int t = 0; t < 4; ++t) *(f32x4*)(pa + t * 16 + 4 * g) = acc[u][t];
      if (g == 0) {
        float2 st = make_float2(m_run[u], lv);
        *(float2*)(pml + ((size_t)tile * NS + sp) * 32 + li * 2) = st;
      }
    }
  }
}

// combine split-KV partials -> aout bf16
__global__ __launch_bounds__(256) void k_combine(const float* __restrict__ pacc,
                                                 const float* __restrict__ pml,
                                                 unsigned short* __restrict__ aout, int NS) {
  int tile = blockIdx.x;  // bh*128 + qt
  int bh = tile >> 7, qt = tile & 127;
  int b = bh / 9, h = bh - b * 9;
  int d = threadIdx.x & 63, q0 = threadIdx.x >> 6;
  for (int q = q0; q < 16; q += 4) {
    const float* ml = pml + (size_t)tile * NS * 32 + q * 2;
    float M = -1e30f;
    for (int sp = 0; sp < NS; ++sp) M = fmaxf(M, ml[sp * 32]);
    float num = 0.f, den = 0.f;
    const float* pa = pacc + (size_t)tile * NS * 1024 + q * 64 + d;
    for (int sp = 0; sp < NS; ++sp) {
      float w = __builtin_amdgcn_exp2f(ml[sp * 32] - M);
      den += w * ml[sp * 32 + 1];
      num += w * pa[(size_t)sp * 1024];
    }
    aout[((size_t)(b * 2048 + qt * 16 + q)) * KPAD + h * 64 + d] = f2bf(num / den);
  }
}

// ---------------- launch ----------------

extern "C" void kernel_launch(void* const* d_in, const int* in_sizes, int n_in,
                              void* d_out, int out_size, void* d_ws, size_t ws_size,
                              hipStream_t stream) {
  const float* x  = (const float*)d_in[0];
  const float* y  = (const float*)d_in[1];
  const float* cx = (const float*)d_in[2];
  const float* cy = (const float*)d_in[3];
  const float* Wq = (const float*)d_in[4];
  const float* Wk = (const float*)d_in[5];
  const float* Wv = (const float*)d_in[6];
  const float* Wo = (const float*)d_in[7];
  const float* cs = (const float*)d_in[8];

  char* w = (char*)d_ws;
  auto take = [&](size_t bytes) {
    char* p = w;
    w += (bytes + 255) & ~(size_t)255;
    return p;
  };
  unsigned short* posed_x = (unsigned short*)take((size_t)4096 * KPAD * 2);
  unsigned short* posed_y = (unsigned short*)take((size_t)4096 * KPAD * 2);
  unsigned short* wqT = (unsigned short*)take((size_t)512 * KPAD * 2);
  unsigned short* wkT = (unsigned short*)take((size_t)512 * KPAD * 2);
  unsigned short* wvT = (unsigned short*)take((size_t)576 * KPAD * 2);
  unsigned short* woT = (unsigned short*)take((size_t)512 * KPAD * 2);
  unsigned short* qbuf = (unsigned short*)take((size_t)2 * 9 * 2048 * 64 * 2);
  unsigned short* kbuf = (unsigned short*)take((size_t)2 * 9 * 2048 * 64 * 2);
  unsigned short* vtb  = (unsigned short*)take((size_t)2 * 9 * 64 * 2048 * 2);
  unsigned short* aout = (unsigned short*)take((size_t)4096 * KPAD * 2);

  size_t base_used = (size_t)(w - (char*)d_ws);
  auto fits = [&](int ns) {
    return base_used + (size_t)2304 * ns * (1024 + 32) * 4 + 1024 <= ws_size;
  };
  int NS = fits(4) ? 4 : (fits(2) ? 2 : 1);
  float* pacc = nullptr;
  float* pml = nullptr;
  if (NS > 1) {
    pacc = (float*)take((size_t)2304 * NS * 1024 * 4);
    pml  = (float*)take((size_t)2304 * NS * 32 * 4);
  }

  k_pack_posed2<<<(8192 * (KPAD / 4) + 255) / 256, 256, 0, stream>>>(x, cx, y, cy, posed_x);
  k_pack_w_all<<<dim3(KPAD / 32, 18, 4), 256, 0, stream>>>(Wq, Wk, Wv, Wo, wqT, wkT, wvT, woT);
  k_pack_ch2<<<(8192 * 16 + 255) / 256, 256, 0, stream>>>(cx, cy, qbuf, kbuf, cs);

  const float qsc = 0.125f * LOG2E;
  k_proj<<<dim3(64, 9, 3), 512, 0, stream>>>(posed_x, posed_y, wqT, wkT, wvT,
                                             qbuf, kbuf, vtb, qsc);

  dim3 ga(8, 9, 2 * NS);
  if (NS == 4)      k_attn<4><<<ga, 256, 0, stream>>>(qbuf, kbuf, vtb, aout, pacc, pml);
  else if (NS == 2) k_attn<2><<<ga, 256, 0, stream>>>(qbuf, kbuf, vtb, aout, pacc, pml);
  else              k_attn<1><<<ga, 256, 0, stream>>>(qbuf, kbuf, vtb, aout, pacc, pml);
  if (NS > 1) k_combine<<<2304, 256, 0, stream>>>(pacc, pml, aout, NS);

  k_gemm_out<<<dim3(64, 8), 512, 0, stream>>>(aout, woT, (float*)d_out, 512);
}